// Round 9
// baseline (342.728 us; speedup 1.0000x reference)
//
#include <hip/hip_runtime.h>
#include <hip/hip_bf16.h>

typedef __attribute__((ext_vector_type(8))) short short8;
typedef __attribute__((ext_vector_type(4))) float floatx4;

__device__ inline unsigned short f2bf(float f) {
    unsigned int u = __float_as_uint(f);
    u += 0x7fffu + ((u >> 16) & 1u);           // round-to-nearest-even
    return (unsigned short)(u >> 16);
}

__device__ inline unsigned int pk_bf16(float lo, float hi) {
    __hip_bfloat162 h = __float22bfloat162_rn(float2{lo, hi});
    unsigned int u;
    __builtin_memcpy(&u, &h, 4);
    return u;
}

// ---------------- merged cast fp32 -> bf16 (all 5 tensors, one launch) -----
// Wq is pre-scaled by scale*log2(e) so flash computes exp2(q.k) directly.
__global__ void cast_all_kernel(const float* __restrict__ x,
                                const float* __restrict__ wq,
                                const float* __restrict__ wk,
                                const float* __restrict__ wv,
                                const float* __restrict__ wo,
                                unsigned short* __restrict__ xb,
                                unsigned short* __restrict__ wqkb,
                                unsigned short* __restrict__ wvb,
                                unsigned short* __restrict__ wob) {
    const float C2 = 0.08838834764831845f * 1.4426950408889634f;
    int bid = blockIdx.x;
    const float* src;
    unsigned short* dst;
    int base;
    float sc = 1.0f;
    if (bid < 8192)       { src = x;  dst = xb;             base = bid; }
    else if (bid < 12288) { src = wq; dst = wqkb;           base = bid - 8192; sc = C2; }
    else if (bid < 14336) { src = wk; dst = wqkb + 4194304; base = bid - 12288; }
    else if (bid < 16384) { src = wv; dst = wvb;            base = bid - 14336; }
    else                  { src = wo; dst = wob;            base = bid - 16384; }
    int i = base * 256 + threadIdx.x;   // float4 units
    float4 v = ((const float4*)src)[i];
    ushort4 o;
    o.x = f2bf(v.x * sc); o.y = f2bf(v.y * sc);
    o.z = f2bf(v.z * sc); o.w = f2bf(v.w * sc);
    ((ushort4*)dst)[i] = o;
}

// ---------------- 256x256 8-phase GEMM, race-hardened pipeline -------------
// (PROVEN r7/r8.) Stage runs TWO K-tiles ahead, 4 slots: iter t reads slot
// t&3, stages tile t+2 into slot of tile t-2 (reads retired two top-barriers
// ago). Boundary wait = counted vmcnt(4). Per tile 2 phases, each {ds_read ||
// stage -> barrier -> lgkmcnt(0) -> sched_barrier -> setprio(1) -> 16 MFMA}.
// Chunk = 16 rows x 32 cols (1KB): lane l -> row c*16+(l>>2), lds k-slot l&3
// holds global k-chunk (l&3)^(row&3); frag read slot = lq^(l16&3).
template <int OUT_BF16>
__device__ __forceinline__ void gemm256_body(
        const unsigned short* __restrict__ A,
        const unsigned short* __restrict__ B,
        void* __restrict__ Cp, int ldc, int m0, int n0,
        unsigned short* sL) {
    const int tid  = threadIdx.x;
    const int wave = tid >> 6;
    const int lane = tid & 63;
    const int l16  = lane & 15;
    const int lq   = lane >> 4;
    const int wm   = (wave >> 2) * 128;
    const int wn   = (wave & 3) * 64;
    const int kx   = lq ^ (l16 & 3);

    floatx4 acc[8][4] = {};

    const unsigned short* gA[2];
    const unsigned short* gB[2];
#pragma unroll
    for (int i = 0; i < 2; i++) {
        int c   = wave * 2 + i;
        int row = c * 16 + (lane >> 2);
        int g   = (lane & 3) ^ (row & 3);
        gA[i] = A + (size_t)(m0 + row) * 2048 + g * 8;
        gB[i] = B + (size_t)(n0 + row) * 2048 + g * 8;
    }

#define STG_A32(slot)                                                          \
    do {                                                                       \
        _Pragma("unroll")                                                      \
        for (int i = 0; i < 2; i++) {                                          \
            __builtin_amdgcn_global_load_lds(                                  \
                (const __attribute__((address_space(1))) void*)gA[i],          \
                (__attribute__((address_space(3))) void*)(sL + (slot) * 16384 +\
                                                          (wave * 2 + i) * 512),\
                16, 0, 0);                                                     \
            gA[i] += 32;                                                       \
        }                                                                      \
    } while (0)
#define STG_B32(slot)                                                          \
    do {                                                                       \
        _Pragma("unroll")                                                      \
        for (int i = 0; i < 2; i++) {                                          \
            __builtin_amdgcn_global_load_lds(                                  \
                (const __attribute__((address_space(1))) void*)gB[i],          \
                (__attribute__((address_space(3))) void*)(sL + (slot) * 16384 +\
                                                  8192 + (wave * 2 + i) * 512),\
                16, 0, 0);                                                     \
            gB[i] += 32;                                                       \
        }                                                                      \
    } while (0)

    // prologue: stage tiles 0,1 into slots 0,1 (8 loads/wave in flight)
    STG_A32(0); STG_B32(0);
    STG_A32(1); STG_B32(1);

    for (int t = 0; t < 64; t++) {
        const int sc = t & 3;
        const int sn = (t + 2) & 3;        // slot of tile t-2 (retired reads)
        // boundary: retire tile t's 4 loads; tile t+1 stays in flight
        if (t < 63) asm volatile("s_waitcnt vmcnt(4)" ::: "memory");
        else        asm volatile("s_waitcnt vmcnt(0)" ::: "memory");
        __builtin_amdgcn_s_barrier();
        asm volatile("" ::: "memory");

        const unsigned short* sAc = sL + sc * 16384;
        const unsigned short* sBc = sAc + 8192;
        short8 af[4], bf[4];

        // ---- phase 0: mh0 (mb 0-3) ----
#pragma unroll
        for (int mb = 0; mb < 4; mb++)
            af[mb] = *(const short8*)(sAc + (wm + mb * 16 + l16) * 32 + kx * 8);
#pragma unroll
        for (int nb = 0; nb < 4; nb++)
            bf[nb] = *(const short8*)(sBc + (wn + nb * 16 + l16) * 32 + kx * 8);
        if (t < 62) STG_A32(sn);
        __builtin_amdgcn_s_barrier();
        asm volatile("s_waitcnt lgkmcnt(0)" ::: "memory");
        __builtin_amdgcn_sched_barrier(0);
        __builtin_amdgcn_s_setprio(1);
#pragma unroll
        for (int mb = 0; mb < 4; mb++)
#pragma unroll
            for (int nb = 0; nb < 4; nb++)
                acc[mb][nb] = __builtin_amdgcn_mfma_f32_16x16x32_bf16(
                    af[mb], bf[nb], acc[mb][nb], 0, 0, 0);
        __builtin_amdgcn_s_setprio(0);
        __builtin_amdgcn_s_barrier();
        asm volatile("" ::: "memory");

        // ---- phase 1: mh1 (mb 4-7), bf reused from registers ----
#pragma unroll
        for (int mb = 0; mb < 4; mb++)
            af[mb] = *(const short8*)(sAc + (wm + 64 + mb * 16 + l16) * 32 + kx * 8);
        if (t < 62) STG_B32(sn);
        __builtin_amdgcn_s_barrier();
        asm volatile("s_waitcnt lgkmcnt(0)" ::: "memory");
        __builtin_amdgcn_sched_barrier(0);
        __builtin_amdgcn_s_setprio(1);
#pragma unroll
        for (int mb = 0; mb < 4; mb++)
#pragma unroll
            for (int nb = 0; nb < 4; nb++)
                acc[4 + mb][nb] = __builtin_amdgcn_mfma_f32_16x16x32_bf16(
                    af[mb], bf[nb], acc[4 + mb][nb], 0, 0, 0);
        __builtin_amdgcn_s_setprio(0);
        // tile closed by next iteration's vmcnt + barrier
    }
#undef STG_A32
#undef STG_B32

#pragma unroll
    for (int mb = 0; mb < 8; mb++)
#pragma unroll
        for (int nb = 0; nb < 4; nb++)
#pragma unroll
            for (int r = 0; r < 4; r++) {
                int row = m0 + wm + mb * 16 + lq * 4 + r;
                int col = n0 + wn + nb * 16 + l16;
                if (OUT_BF16)
                    ((unsigned short*)Cp)[(size_t)row * ldc + col] = f2bf(acc[mb][nb][r]);
                else
                    ((float*)Cp)[(size_t)row * ldc + col] = acc[mb][nb][r];
            }
}

// ---------------- 128x256 single-phase variant (same hardened pipeline) ----
// (PROVEN r8.) 256 blocks = 1/CU for gemm_o. One phase/tile; counted
// vmcnt(3); stage 2 ahead into slot of tile t-2; 4 slots x 24 KB = 96 KB.
template <int OUT_BF16>
__device__ __forceinline__ void gemm128_body(
        const unsigned short* __restrict__ A,
        const unsigned short* __restrict__ B,
        void* __restrict__ Cp, int ldc, int m0, int n0,
        unsigned short* sL) {
    const int tid  = threadIdx.x;
    const int wave = tid >> 6;
    const int lane = tid & 63;
    const int l16  = lane & 15;
    const int lq   = lane >> 4;
    const int wm   = (wave >> 2) * 64;
    const int wn   = (wave & 3) * 64;
    const int kx   = lq ^ (l16 & 3);

    floatx4 acc[4][4] = {};

    const unsigned short* gA0;
    const unsigned short* gB[2];
    {
        int row = wave * 16 + (lane >> 2);              // A chunk = wave
        int g   = (lane & 3) ^ (row & 3);
        gA0 = A + (size_t)(m0 + row) * 2048 + g * 8;
    }
#pragma unroll
    for (int i = 0; i < 2; i++) {
        int c   = wave * 2 + i;                         // B chunks
        int row = c * 16 + (lane >> 2);
        int g   = (lane & 3) ^ (row & 3);
        gB[i] = B + (size_t)(n0 + row) * 2048 + g * 8;
    }

#define STG_O(slot)                                                            \
    do {                                                                       \
        __builtin_amdgcn_global_load_lds(                                      \
            (const __attribute__((address_space(1))) void*)gA0,                \
            (__attribute__((address_space(3))) void*)(sL + (slot) * 12288 +    \
                                                      wave * 512),             \
            16, 0, 0);                                                         \
        gA0 += 32;                                                             \
        _Pragma("unroll")                                                      \
        for (int i = 0; i < 2; i++) {                                          \
            __builtin_amdgcn_global_load_lds(                                  \
                (const __attribute__((address_space(1))) void*)gB[i],          \
                (__attribute__((address_space(3))) void*)(sL + (slot) * 12288 +\
                                                  4096 + (wave * 2 + i) * 512),\
                16, 0, 0);                                                     \
            gB[i] += 32;                                                       \
        }                                                                      \
    } while (0)

    // prologue: stage tiles 0,1 into slots 0,1 (6 loads/wave in flight)
    STG_O(0); STG_O(1);

    for (int t = 0; t < 64; t++) {
        const int sc = t & 3;
        const int sn = (t + 2) & 3;        // slot of tile t-2 (retired reads)
        if (t < 63) asm volatile("s_waitcnt vmcnt(3)" ::: "memory");
        else        asm volatile("s_waitcnt vmcnt(0)" ::: "memory");
        __builtin_amdgcn_s_barrier();
        asm volatile("" ::: "memory");

        const unsigned short* sAc = sL + sc * 12288;
        const unsigned short* sBc = sAc + 4096;
        short8 af[4], bf[4];
#pragma unroll
        for (int mb = 0; mb < 4; mb++)
            af[mb] = *(const short8*)(sAc + (wm + mb * 16 + l16) * 32 + kx * 8);
#pragma unroll
        for (int nb = 0; nb < 4; nb++)
            bf[nb] = *(const short8*)(sBc + (wn + nb * 16 + l16) * 32 + kx * 8);
        if (t < 62) STG_O(sn);
        __builtin_amdgcn_s_barrier();
        asm volatile("s_waitcnt lgkmcnt(0)" ::: "memory");
        __builtin_amdgcn_sched_barrier(0);
        __builtin_amdgcn_s_setprio(1);
#pragma unroll
        for (int mb = 0; mb < 4; mb++)
#pragma unroll
            for (int nb = 0; nb < 4; nb++)
                acc[mb][nb] = __builtin_amdgcn_mfma_f32_16x16x32_bf16(
                    af[mb], bf[nb], acc[mb][nb], 0, 0, 0);
        __builtin_amdgcn_s_setprio(0);
        // tile closed by next iteration's vmcnt + barrier
    }
#undef STG_O

#pragma unroll
    for (int mb = 0; mb < 4; mb++)
#pragma unroll
        for (int nb = 0; nb < 4; nb++)
#pragma unroll
            for (int r = 0; r < 4; r++) {
                int row = m0 + wm + mb * 16 + lq * 4 + r;
                int col = n0 + wn + nb * 16 + l16;
                if (OUT_BF16)
                    ((unsigned short*)Cp)[(size_t)row * ldc + col] = f2bf(acc[mb][nb][r]);
                else
                    ((float*)Cp)[(size_t)row * ldc + col] = acc[mb][nb][r];
            }
}

// ---------------- merged QK + Vt gemm (256 blocks = 1/CU) ------------------
__global__ __launch_bounds__(512, 1) void gemm_qkv_kernel(
        const unsigned short* __restrict__ x_bf,
        const unsigned short* __restrict__ Wqk,
        const unsigned short* __restrict__ Wv,
        unsigned short* __restrict__ QKb,
        unsigned short* __restrict__ Vtb) {
    __shared__ __align__(16) unsigned short sL[4 * 16384];   // 128 KB
    const int bid = blockIdx.x;
    if (bid < 192) {
        // QK = x @ [Wq;Wk]^T : M=4096 N=3072 (16 x 12 tiles of 256)
        gemm256_body<1>(x_bf, Wqk, QKb, 3072,
                        (bid / 12) * 256, (bid % 12) * 256, sL);
    } else {
        // Vt = Wv @ x^T : M=1024 N=4096 (4 x 16 tiles of 256)
        int t = bid - 192;
        gemm256_body<1>(Wv, x_bf, Vtb, 4096,
                        (t / 16) * 256, (t % 16) * 256, sL);
    }
}

// ---------------- O-proj gemm (fp32 out, 256 blocks = 1/CU) ----------------
__global__ __launch_bounds__(512, 1) void gemm_o_kernel(
        const unsigned short* __restrict__ A,
        const unsigned short* __restrict__ B,
        float* __restrict__ C) {
    __shared__ __align__(16) unsigned short sL[4 * 12288];   // 96 KB
    gemm128_body<0>(A, B, C, 2048,
                    blockIdx.y * 128, blockIdx.x * 256, sL);
}

// ---------------- flash attention v6: 48 KB LDS -> 3 blocks/CU -------------
// Same per-kt compute/swizzles as proven v4; buffering changed:
//  - SINGLE-buffered sK(16K)+sV(16K)+sP(16K) = 48 KB -> 3 blocks/CU
//    (was 80 KB / 2 blocks; occupancy 19% -> ~28%: the untried lever —
//    no pipe >50% at 2 blocks, so latency-bound; TLP +50%)
//  - split-lifetime staging: K's last read is QK ks1, so stage K(kt+1)
//    right after barrier#1 and hide its latency under PV ks1's ds_reads +
//    16 MFMAs; stage V(kt+1) after barrier#2 (last sV read); vmcnt(0) then
//    barrier#3. K/V slices are ~86% L2-resident (32 blocks share each) so
//    the exposed V latency is ~200-300 cyc/kt, amortized over 3 blocks.
__global__ __launch_bounds__(256, 3) void flash_kernel(
        const unsigned short* __restrict__ QK,
        const unsigned short* __restrict__ Vt,
        unsigned short* __restrict__ O) {
    // layout (ushorts): sK[8192] @0, sV[8192] @8192, sP[4][2048] @16384
    __shared__ __align__(16) unsigned short smem[24576];

    const int tid  = threadIdx.x;
    const int wave = tid >> 6;
    const int lane = tid & 63;
    const int l16  = lane & 15;
    const int lq   = lane >> 4;
    const int qt   = blockIdx.x;          // 0..15 (128 tokens each)
    const int bh   = blockIdx.y;
    const int b    = bh >> 4;
    const int h    = bh & 15;
    const int kvh  = h >> 1;
    const size_t tokbase = (size_t)b * 2048 + qt * 128 + wave * 32;

    // Q fragments: 32 rows x 128 d per wave (B-operand, col = q = l16)
    short8 qf[2][4];
#pragma unroll
    for (int qb = 0; qb < 2; qb++) {
        const unsigned short* qp =
            QK + (tokbase + qb * 16 + l16) * 3072 + h * 128 + lq * 8;
#pragma unroll
        for (int c = 0; c < 4; c++) qf[qb][c] = *(const short8*)(qp + c * 32);
    }

    const unsigned short* gKe =
        QK + ((size_t)b * 2048 + wave * 16 + lq) * 3072 + 2048 + kvh * 128 +
        (l16 ^ lq) * 8;
    const unsigned short* gKo =
        QK + ((size_t)b * 2048 + wave * 16 + 4 + lq) * 3072 + 2048 + kvh * 128 +
        (l16 ^ (lq + 4)) * 8;
    const unsigned short* gV0 =
        Vt + (size_t)(kvh * 128 + wave * 32 + (lane >> 3)) * 4096 +
        (size_t)b * 2048 + ((lane & 7) ^ (lane >> 3)) * 8;

    unsigned short* sK = smem;
    unsigned short* sV = smem + 8192;

#define STAGE_K()                                                              \
    do {                                                                       \
        _Pragma("unroll")                                                      \
        for (int i = 0; i < 4; i++) {                                          \
            const unsigned short* gk =                                         \
                ((i & 1) ? gKo : gKe) + (i >> 1) * 24576;                      \
            __builtin_amdgcn_global_load_lds(                                  \
                (const __attribute__((address_space(1))) void*)gk,             \
                (__attribute__((address_space(3))) void*)(sK +                 \
                                                          (wave * 4 + i) * 512),\
                16, 0, 0);                                                     \
        }                                                                      \
        gKe += 196608; gKo += 196608;                                          \
    } while (0)
#define STAGE_V()                                                              \
    do {                                                                       \
        _Pragma("unroll")                                                      \
        for (int i = 0; i < 4; i++) {                                          \
            __builtin_amdgcn_global_load_lds(                                  \
                (const __attribute__((address_space(1))) void*)(gV0 +          \
                                                               i * 32768),     \
                (__attribute__((address_space(3))) void*)(sV +                 \
                                                          (wave * 4 + i) * 512),\
                16, 0, 0);                                                     \
        }                                                                      \
        gV0 += 64;                                                             \
    } while (0)

    unsigned short* pB = smem + 16384 + wave * 2048;

    floatx4 oacc[2][8] = {};
    float l_run[2] = {0.0f, 0.0f};

    // prologue: stage tile 0, drain, barrier
    STAGE_K();
    STAGE_V();
    asm volatile("s_waitcnt vmcnt(0)" ::: "memory");
    __builtin_amdgcn_s_barrier();
    asm volatile("" ::: "memory");

    for (int kt = 0; kt < 32; kt++) {
        // ===== ks0: QK over kb=0,1 + softmax + P write (keys 0..31) =====
#pragma unroll
        for (int kb = 0; kb < 2; kb++) {
            floatx4 sacc[2] = {};
#pragma unroll
            for (int c = 0; c < 4; c++) {
                short8 kf = *(const short8*)(
                    sK + (kb * 16 + l16) * 128 + (((c * 4 + lq) ^ (l16 & 7)) * 8));
#pragma unroll
                for (int qb = 0; qb < 2; qb++)
                    sacc[qb] = __builtin_amdgcn_mfma_f32_16x16x32_bf16(
                        kf, qf[qb][c], sacc[qb], 0, 0, 0);
            }
#pragma unroll
            for (int qb = 0; qb < 2; qb++) {
                float p0 = __builtin_exp2f(sacc[qb][0]);
                float p1 = __builtin_exp2f(sacc[qb][1]);
                float p2 = __builtin_exp2f(sacc[qb][2]);
                float p3 = __builtin_exp2f(sacc[qb][3]);
                l_run[qb] += (p0 + p1) + (p2 + p3);
                int row = qb * 16 + l16;
                uint2 u;
                u.x = pk_bf16(p0, p1);
                u.y = pk_bf16(p2, p3);
                *(uint2*)(pB + row * 64 +
                          (((kb * 2 + (lq >> 1)) ^ (row & 7)) * 8) +
                          (lq & 1) * 4) = u;
            }
        }
        asm volatile("s_waitcnt lgkmcnt(0)" ::: "memory");

        short8 pf0[2];
#pragma unroll
        for (int qb = 0; qb < 2; qb++) {
            int row = qb * 16 + l16;
            pf0[qb] = *(const short8*)(pB + row * 64 +
                                       ((lq ^ (row & 7)) * 8));
        }

        // ===== PV(ks0) =====
        __builtin_amdgcn_s_setprio(1);
#pragma unroll
        for (int nb = 0; nb < 8; nb++) {
            short8 vf = *(const short8*)(
                sV + (nb * 16 + l16) * 64 + ((lq ^ (l16 & 7)) * 8));
#pragma unroll
            for (int qb = 0; qb < 2; qb++)
                oacc[qb][nb] = __builtin_amdgcn_mfma_f32_16x16x32_bf16(
                    vf, pf0[qb], oacc[qb][nb], 0, 0, 0);
        }
        __builtin_amdgcn_s_setprio(0);

        // ===== ks1: QK over kb=2,3 + softmax + P write (keys 32..63) =====
#pragma unroll
        for (int kb = 2; kb < 4; kb++) {
            floatx4 sacc[2] = {};
#pragma unroll
            for (int c = 0; c < 4; c++) {
                short8 kf = *(const short8*)(
                    sK + (kb * 16 + l16) * 128 + (((c * 4 + lq) ^ (l16 & 7)) * 8));
#pragma unroll
                for (int qb = 0; qb < 2; qb++)
                    sacc[qb] = __builtin_amdgcn_mfma_f32_16x16x32_bf16(
                        kf, qf[qb][c], sacc[qb], 0, 0, 0);
            }
#pragma unroll
            for (int qb = 0; qb < 2; qb++) {
                float p0 = __builtin_exp2f(sacc[qb][0]);
                float p1 = __builtin_exp2f(sacc[qb][1]);
                float p2 = __builtin_exp2f(sacc[qb][2]);
                float p3 = __builtin_exp2f(sacc[qb][3]);
                l_run[qb] += (p0 + p1) + (p2 + p3);
                int row = qb * 16 + l16;
                uint2 u;
                u.x = pk_bf16(p0, p1);
                u.y = pk_bf16(p2, p3);
                *(uint2*)(pB + row * 64 +
                          (((kb * 2 + (lq >> 1)) ^ (row & 7)) * 8) +
                          (lq & 1) * 4) = u;
            }
        }
        asm volatile("s_waitcnt lgkmcnt(0)" ::: "memory");

        // barrier #1: all waves done with sK (QK ks1 was the last K read)
        __builtin_amdgcn_s_barrier();
        asm volatile("" ::: "memory");
        if (kt < 31) STAGE_K();          // K(kt+1) hides under PV ks1

        short8 pf1[2];
#pragma unroll
        for (int qb = 0; qb < 2; qb++) {
            int row = qb * 16 + l16;
            pf1[qb] = *(const short8*)(pB + row * 64 +
                                       (((4 + lq) ^ (row & 7)) * 8));
        }

        // ===== PV(ks1) =====
        __builtin_amdgcn_s_setprio(1);
#pragma unroll
        for (int nb = 0; nb < 8; nb++) {
            short8 vf = *(const short8*)(
                sV + (nb * 16 + l16) * 64 + (((4 + lq) ^ (l16 & 7)) * 8));
#pragma unroll
            for (int qb = 0; qb < 2; qb++)
                oacc[qb][nb] = __builtin_amdgcn_mfma_f32_16x16x32_bf16(
                    vf, pf1[qb], oacc[qb][nb], 0, 0, 0);
        }
        __builtin_amdgcn_s_setprio(0);

        // barrier #2: all waves done with sV (PV ks1 was the last V read)
        asm volatile("s_waitcnt lgkmcnt(0)" ::: "memory");
        __builtin_amdgcn_s_barrier();
        asm volatile("" ::: "memory");
        if (kt < 31) STAGE_V();          // V(kt+1)

        // barrier #3: tile kt+1 fully landed for everyone
        asm volatile("s_waitcnt vmcnt(0)" ::: "memory");
        __builtin_amdgcn_s_barrier();
        asm volatile("" ::: "memory");
    }
#undef STAGE_K
#undef STAGE_V

#pragma unroll
    for (int qb = 0; qb < 2; qb++) {
        float l = l_run[qb];
        l += __shfl_xor(l, 16);
        l += __shfl_xor(l, 32);
        float inv = 1.0f / l;
        size_t row = (tokbase + qb * 16 + l16) * 2048 + h * 128;
#pragma unroll
        for (int nb = 0; nb < 8; nb++) {
            uint2 u;
            u.x = pk_bf16(oacc[qb][nb][0] * inv, oacc[qb][nb][1] * inv);
            u.y = pk_bf16(oacc[qb][nb][2] * inv, oacc[qb][nb][3] * inv);
            *(uint2*)(O + row + nb * 16 + lq * 4) = u;
        }
    }
}

// ---------------- launcher ----------------
extern "C" void kernel_launch(void* const* d_in, const int* in_sizes, int n_in,
                              void* d_out, int out_size, void* d_ws, size_t ws_size,
                              hipStream_t stream) {
    const float* x  = (const float*)d_in[0];
    const float* Wq = (const float*)d_in[1];
    const float* Wk = (const float*)d_in[2];
    const float* Wv = (const float*)d_in[3];
    const float* Wo = (const float*)d_in[4];

    char* ws = (char*)d_ws;
    unsigned short* x_bf   = (unsigned short*)(ws);               // 16 MB
    unsigned short* Wqk_bf = (unsigned short*)(ws + 16777216);    // 12 MB (Wq;Wk)
    unsigned short* Wv_bf  = (unsigned short*)(ws + 29360128);    // 4 MB
    unsigned short* Wo_bf  = (unsigned short*)(ws + 33554432);    // 8 MB
    unsigned short* QKb    = (unsigned short*)(ws + 41943040);    // 24 MB (4096x3072)
    unsigned short* Vtb    = (unsigned short*)(ws + 67108864);    // 8 MB  (1024x4096)
    unsigned short* Ob     = (unsigned short*)(ws + 75497472);    // 16 MB (4096x2048)

    cast_all_kernel<<<dim3(20480), 256, 0, stream>>>(
        x, Wq, Wk, Wv, Wo, x_bf, Wqk_bf, Wv_bf, Wo_bf);

    // QK = x @ [Wq;Wk]^T  and  Vt = Wv @ x^T (256 blocks = 1/CU, 512 thr)
    gemm_qkv_kernel<<<dim3(256), 512, 0, stream>>>(x_bf, Wqk_bf, Wv_bf, QKb, Vtb);

    // flash attention: 128 tokens/block
    flash_kernel<<<dim3(16, 32), 256, 0, stream>>>(QKb, Vtb, Ob);

    // out = O @ Wo^T : M=4096, N=2048, K=2048, fp32 out (32 x 8 tiles)
    gemm_o_kernel<<<dim3(8, 32), 512, 0, stream>>>(Ob, Wo_bf, (float*)d_out);
}

// Round 10
// 313.636 us; speedup vs baseline: 1.0928x; 1.0928x over previous
//
#include <hip/hip_runtime.h>
#include <hip/hip_bf16.h>

typedef __attribute__((ext_vector_type(8))) short short8;
typedef __attribute__((ext_vector_type(4))) float floatx4;

__device__ inline unsigned short f2bf(float f) {
    unsigned int u = __float_as_uint(f);
    u += 0x7fffu + ((u >> 16) & 1u);           // round-to-nearest-even
    return (unsigned short)(u >> 16);
}

__device__ inline unsigned int pk_bf16(float lo, float hi) {
    __hip_bfloat162 h = __float22bfloat162_rn(float2{lo, hi});
    unsigned int u;
    __builtin_memcpy(&u, &h, 4);
    return u;
}

// ---------------- merged cast fp32 -> bf16 (all 5 tensors, one launch) -----
// Wq is pre-scaled by scale*log2(e) so flash computes exp2(q.k) directly.
__global__ void cast_all_kernel(const float* __restrict__ x,
                                const float* __restrict__ wq,
                                const float* __restrict__ wk,
                                const float* __restrict__ wv,
                                const float* __restrict__ wo,
                                unsigned short* __restrict__ xb,
                                unsigned short* __restrict__ wqkb,
                                unsigned short* __restrict__ wvb,
                                unsigned short* __restrict__ wob) {
    const float C2 = 0.08838834764831845f * 1.4426950408889634f;
    int bid = blockIdx.x;
    const float* src;
    unsigned short* dst;
    int base;
    float sc = 1.0f;
    if (bid < 8192)       { src = x;  dst = xb;             base = bid; }
    else if (bid < 12288) { src = wq; dst = wqkb;           base = bid - 8192; sc = C2; }
    else if (bid < 14336) { src = wk; dst = wqkb + 4194304; base = bid - 12288; }
    else if (bid < 16384) { src = wv; dst = wvb;            base = bid - 14336; }
    else                  { src = wo; dst = wob;            base = bid - 16384; }
    int i = base * 256 + threadIdx.x;   // float4 units
    float4 v = ((const float4*)src)[i];
    ushort4 o;
    o.x = f2bf(v.x * sc); o.y = f2bf(v.y * sc);
    o.z = f2bf(v.z * sc); o.w = f2bf(v.w * sc);
    ((ushort4*)dst)[i] = o;
}

// ---------------- 256x256 8-phase GEMM, race-hardened pipeline -------------
// (PROVEN r7/r8.) Stage runs TWO K-tiles ahead, 4 slots: iter t reads slot
// t&3, stages tile t+2 into slot of tile t-2 (reads retired two top-barriers
// ago). Boundary wait = counted vmcnt(4). Per tile 2 phases, each {ds_read ||
// stage -> barrier -> lgkmcnt(0) -> sched_barrier -> setprio(1) -> 16 MFMA}.
// Chunk = 16 rows x 32 cols (1KB): lane l -> row c*16+(l>>2), lds k-slot l&3
// holds global k-chunk (l&3)^(row&3); frag read slot = lq^(l16&3).
template <int OUT_BF16>
__device__ __forceinline__ void gemm256_body(
        const unsigned short* __restrict__ A,
        const unsigned short* __restrict__ B,
        void* __restrict__ Cp, int ldc, int m0, int n0,
        unsigned short* sL) {
    const int tid  = threadIdx.x;
    const int wave = tid >> 6;
    const int lane = tid & 63;
    const int l16  = lane & 15;
    const int lq   = lane >> 4;
    const int wm   = (wave >> 2) * 128;
    const int wn   = (wave & 3) * 64;
    const int kx   = lq ^ (l16 & 3);

    floatx4 acc[8][4] = {};

    const unsigned short* gA[2];
    const unsigned short* gB[2];
#pragma unroll
    for (int i = 0; i < 2; i++) {
        int c   = wave * 2 + i;
        int row = c * 16 + (lane >> 2);
        int g   = (lane & 3) ^ (row & 3);
        gA[i] = A + (size_t)(m0 + row) * 2048 + g * 8;
        gB[i] = B + (size_t)(n0 + row) * 2048 + g * 8;
    }

#define STG_A32(slot)                                                          \
    do {                                                                       \
        _Pragma("unroll")                                                      \
        for (int i = 0; i < 2; i++) {                                          \
            __builtin_amdgcn_global_load_lds(                                  \
                (const __attribute__((address_space(1))) void*)gA[i],          \
                (__attribute__((address_space(3))) void*)(sL + (slot) * 16384 +\
                                                          (wave * 2 + i) * 512),\
                16, 0, 0);                                                     \
            gA[i] += 32;                                                       \
        }                                                                      \
    } while (0)
#define STG_B32(slot)                                                          \
    do {                                                                       \
        _Pragma("unroll")                                                      \
        for (int i = 0; i < 2; i++) {                                          \
            __builtin_amdgcn_global_load_lds(                                  \
                (const __attribute__((address_space(1))) void*)gB[i],          \
                (__attribute__((address_space(3))) void*)(sL + (slot) * 16384 +\
                                                  8192 + (wave * 2 + i) * 512),\
                16, 0, 0);                                                     \
            gB[i] += 32;                                                       \
        }                                                                      \
    } while (0)

    // prologue: stage tiles 0,1 into slots 0,1 (8 loads/wave in flight)
    STG_A32(0); STG_B32(0);
    STG_A32(1); STG_B32(1);

    for (int t = 0; t < 64; t++) {
        const int sc = t & 3;
        const int sn = (t + 2) & 3;        // slot of tile t-2 (retired reads)
        // boundary: retire tile t's 4 loads; tile t+1 stays in flight
        if (t < 63) asm volatile("s_waitcnt vmcnt(4)" ::: "memory");
        else        asm volatile("s_waitcnt vmcnt(0)" ::: "memory");
        __builtin_amdgcn_s_barrier();
        asm volatile("" ::: "memory");

        const unsigned short* sAc = sL + sc * 16384;
        const unsigned short* sBc = sAc + 8192;
        short8 af[4], bf[4];

        // ---- phase 0: mh0 (mb 0-3) ----
#pragma unroll
        for (int mb = 0; mb < 4; mb++)
            af[mb] = *(const short8*)(sAc + (wm + mb * 16 + l16) * 32 + kx * 8);
#pragma unroll
        for (int nb = 0; nb < 4; nb++)
            bf[nb] = *(const short8*)(sBc + (wn + nb * 16 + l16) * 32 + kx * 8);
        if (t < 62) STG_A32(sn);
        __builtin_amdgcn_s_barrier();
        asm volatile("s_waitcnt lgkmcnt(0)" ::: "memory");
        __builtin_amdgcn_sched_barrier(0);
        __builtin_amdgcn_s_setprio(1);
#pragma unroll
        for (int mb = 0; mb < 4; mb++)
#pragma unroll
            for (int nb = 0; nb < 4; nb++)
                acc[mb][nb] = __builtin_amdgcn_mfma_f32_16x16x32_bf16(
                    af[mb], bf[nb], acc[mb][nb], 0, 0, 0);
        __builtin_amdgcn_s_setprio(0);
        __builtin_amdgcn_s_barrier();
        asm volatile("" ::: "memory");

        // ---- phase 1: mh1 (mb 4-7), bf reused from registers ----
#pragma unroll
        for (int mb = 0; mb < 4; mb++)
            af[mb] = *(const short8*)(sAc + (wm + 64 + mb * 16 + l16) * 32 + kx * 8);
        if (t < 62) STG_B32(sn);
        __builtin_amdgcn_s_barrier();
        asm volatile("s_waitcnt lgkmcnt(0)" ::: "memory");
        __builtin_amdgcn_sched_barrier(0);
        __builtin_amdgcn_s_setprio(1);
#pragma unroll
        for (int mb = 0; mb < 4; mb++)
#pragma unroll
            for (int nb = 0; nb < 4; nb++)
                acc[4 + mb][nb] = __builtin_amdgcn_mfma_f32_16x16x32_bf16(
                    af[mb], bf[nb], acc[4 + mb][nb], 0, 0, 0);
        __builtin_amdgcn_s_setprio(0);
        // tile closed by next iteration's vmcnt + barrier
    }
#undef STG_A32
#undef STG_B32

#pragma unroll
    for (int mb = 0; mb < 8; mb++)
#pragma unroll
        for (int nb = 0; nb < 4; nb++)
#pragma unroll
            for (int r = 0; r < 4; r++) {
                int row = m0 + wm + mb * 16 + lq * 4 + r;
                int col = n0 + wn + nb * 16 + l16;
                if (OUT_BF16)
                    ((unsigned short*)Cp)[(size_t)row * ldc + col] = f2bf(acc[mb][nb][r]);
                else
                    ((float*)Cp)[(size_t)row * ldc + col] = acc[mb][nb][r];
            }
}

// ---------------- 128x256 single-phase variant (same hardened pipeline) ----
// (PROVEN r8.) 256 blocks = 1/CU for gemm_o. One phase/tile; counted
// vmcnt(3); stage 2 ahead into slot of tile t-2; 4 slots x 24 KB = 96 KB.
template <int OUT_BF16>
__device__ __forceinline__ void gemm128_body(
        const unsigned short* __restrict__ A,
        const unsigned short* __restrict__ B,
        void* __restrict__ Cp, int ldc, int m0, int n0,
        unsigned short* sL) {
    const int tid  = threadIdx.x;
    const int wave = tid >> 6;
    const int lane = tid & 63;
    const int l16  = lane & 15;
    const int lq   = lane >> 4;
    const int wm   = (wave >> 2) * 64;
    const int wn   = (wave & 3) * 64;
    const int kx   = lq ^ (l16 & 3);

    floatx4 acc[4][4] = {};

    const unsigned short* gA0;
    const unsigned short* gB[2];
    {
        int row = wave * 16 + (lane >> 2);              // A chunk = wave
        int g   = (lane & 3) ^ (row & 3);
        gA0 = A + (size_t)(m0 + row) * 2048 + g * 8;
    }
#pragma unroll
    for (int i = 0; i < 2; i++) {
        int c   = wave * 2 + i;                         // B chunks
        int row = c * 16 + (lane >> 2);
        int g   = (lane & 3) ^ (row & 3);
        gB[i] = B + (size_t)(n0 + row) * 2048 + g * 8;
    }

#define STG_O(slot)                                                            \
    do {                                                                       \
        __builtin_amdgcn_global_load_lds(                                      \
            (const __attribute__((address_space(1))) void*)gA0,                \
            (__attribute__((address_space(3))) void*)(sL + (slot) * 12288 +    \
                                                      wave * 512),             \
            16, 0, 0);                                                         \
        gA0 += 32;                                                             \
        _Pragma("unroll")                                                      \
        for (int i = 0; i < 2; i++) {                                          \
            __builtin_amdgcn_global_load_lds(                                  \
                (const __attribute__((address_space(1))) void*)gB[i],          \
                (__attribute__((address_space(3))) void*)(sL + (slot) * 12288 +\
                                                  4096 + (wave * 2 + i) * 512),\
                16, 0, 0);                                                     \
            gB[i] += 32;                                                       \
        }                                                                      \
    } while (0)

    // prologue: stage tiles 0,1 into slots 0,1 (6 loads/wave in flight)
    STG_O(0); STG_O(1);

    for (int t = 0; t < 64; t++) {
        const int sc = t & 3;
        const int sn = (t + 2) & 3;        // slot of tile t-2 (retired reads)
        if (t < 63) asm volatile("s_waitcnt vmcnt(3)" ::: "memory");
        else        asm volatile("s_waitcnt vmcnt(0)" ::: "memory");
        __builtin_amdgcn_s_barrier();
        asm volatile("" ::: "memory");

        const unsigned short* sAc = sL + sc * 12288;
        const unsigned short* sBc = sAc + 4096;
        short8 af[4], bf[4];
#pragma unroll
        for (int mb = 0; mb < 4; mb++)
            af[mb] = *(const short8*)(sAc + (wm + mb * 16 + l16) * 32 + kx * 8);
#pragma unroll
        for (int nb = 0; nb < 4; nb++)
            bf[nb] = *(const short8*)(sBc + (wn + nb * 16 + l16) * 32 + kx * 8);
        if (t < 62) STG_O(sn);
        __builtin_amdgcn_s_barrier();
        asm volatile("s_waitcnt lgkmcnt(0)" ::: "memory");
        __builtin_amdgcn_sched_barrier(0);
        __builtin_amdgcn_s_setprio(1);
#pragma unroll
        for (int mb = 0; mb < 4; mb++)
#pragma unroll
            for (int nb = 0; nb < 4; nb++)
                acc[mb][nb] = __builtin_amdgcn_mfma_f32_16x16x32_bf16(
                    af[mb], bf[nb], acc[mb][nb], 0, 0, 0);
        __builtin_amdgcn_s_setprio(0);
        // tile closed by next iteration's vmcnt + barrier
    }
#undef STG_O

#pragma unroll
    for (int mb = 0; mb < 4; mb++)
#pragma unroll
        for (int nb = 0; nb < 4; nb++)
#pragma unroll
            for (int r = 0; r < 4; r++) {
                int row = m0 + wm + mb * 16 + lq * 4 + r;
                int col = n0 + wn + nb * 16 + l16;
                if (OUT_BF16)
                    ((unsigned short*)Cp)[(size_t)row * ldc + col] = f2bf(acc[mb][nb][r]);
                else
                    ((float*)Cp)[(size_t)row * ldc + col] = acc[mb][nb][r];
            }
}

// ---------------- merged QK + Vt gemm (256 blocks = 1/CU, XCD-chunked) -----
// T1 swizzle (nwg=256, 256%8==0 -> bijective): physical p -> logical
// bid=(p&7)*32+(p>>3). Each XCD gets 32 contiguous logical tiles ->
// A-panel reuse stays in one per-XCD L2. Side effect: Vt tiles (bid>=192)
// land entirely on XCDs 6,7 -> Wv (4MB) resident there; per-XCD block
// count balanced (32 each, identical tile work).
__global__ __launch_bounds__(512, 1) void gemm_qkv_kernel(
        const unsigned short* __restrict__ x_bf,
        const unsigned short* __restrict__ Wqk,
        const unsigned short* __restrict__ Wv,
        unsigned short* __restrict__ QKb,
        unsigned short* __restrict__ Vtb) {
    __shared__ __align__(16) unsigned short sL[4 * 16384];   // 128 KB
    const int p   = blockIdx.x;
    const int bid = (p & 7) * 32 + (p >> 3);
    if (bid < 192) {
        // QK = x @ [Wq;Wk]^T : M=4096 N=3072 (16 x 12 tiles of 256)
        gemm256_body<1>(x_bf, Wqk, QKb, 3072,
                        (bid / 12) * 256, (bid % 12) * 256, sL);
    } else {
        // Vt = Wv @ x^T : M=1024 N=4096 (4 x 16 tiles of 256)
        int t = bid - 192;
        gemm256_body<1>(Wv, x_bf, Vtb, 4096,
                        (t / 16) * 256, (t % 16) * 256, sL);
    }
}

// ---------------- O-proj gemm (fp32 out, 256 blocks, XCD-chunked) ----------
__global__ __launch_bounds__(512, 1) void gemm_o_kernel(
        const unsigned short* __restrict__ A,
        const unsigned short* __restrict__ B,
        float* __restrict__ C) {
    __shared__ __align__(16) unsigned short sL[4 * 12288];   // 96 KB
    const int p = blockIdx.x;
    const int t = (p & 7) * 32 + (p >> 3);   // bijective, nwg=256
    gemm128_body<0>(A, B, C, 2048,
                    (t >> 3) * 128, (t & 7) * 256, sL);
}

// ---------------- flash attention v4 (proven plateau: ~99 us) ---------------
// Six structural variants (r0-r9) all land 99-112 us; this is the best.
// 4 waves = 4 q-slices (32 q-rows each), all 64 keys/wave; double-buffered
// sK/sV + wave-private sP (80 KB, 2 blocks/CU — grid 512 caps at 2/CU
// anyway, so LDS is free); two 32-key PV steps interleave with QK/softmax.
__global__ __launch_bounds__(256, 2) void flash_kernel(
        const unsigned short* __restrict__ QK,
        const unsigned short* __restrict__ Vt,
        unsigned short* __restrict__ O) {
    // layout (ushorts): sK[2][8192] @0, sV[2][8192] @16384, sP[4][2048] @32768
    __shared__ __align__(16) unsigned short smem[40960];

    const int tid  = threadIdx.x;
    const int wave = tid >> 6;
    const int lane = tid & 63;
    const int l16  = lane & 15;
    const int lq   = lane >> 4;
    const int qt   = blockIdx.x;          // 0..15 (128 tokens each)
    const int bh   = blockIdx.y;
    const int b    = bh >> 4;
    const int h    = bh & 15;
    const int kvh  = h >> 1;
    const size_t tokbase = (size_t)b * 2048 + qt * 128 + wave * 32;

    // Q fragments: 32 rows x 128 d per wave (B-operand, col = q = l16)
    short8 qf[2][4];
#pragma unroll
    for (int qb = 0; qb < 2; qb++) {
        const unsigned short* qp =
            QK + (tokbase + qb * 16 + l16) * 3072 + h * 128 + lq * 8;
#pragma unroll
        for (int c = 0; c < 4; c++) qf[qb][c] = *(const short8*)(qp + c * 32);
    }

    const unsigned short* gKe =
        QK + ((size_t)b * 2048 + wave * 16 + lq) * 3072 + 2048 + kvh * 128 +
        (l16 ^ lq) * 8;
    const unsigned short* gKo =
        QK + ((size_t)b * 2048 + wave * 16 + 4 + lq) * 3072 + 2048 + kvh * 128 +
        (l16 ^ (lq + 4)) * 8;
    const unsigned short* gV0 =
        Vt + (size_t)(kvh * 128 + wave * 32 + (lane >> 3)) * 4096 +
        (size_t)b * 2048 + ((lane & 7) ^ (lane >> 3)) * 8;

#define STAGE_KT(sKd, sVd)                                                     \
    do {                                                                       \
        _Pragma("unroll")                                                      \
        for (int i = 0; i < 4; i++) {                                          \
            const unsigned short* gk =                                         \
                ((i & 1) ? gKo : gKe) + (i >> 1) * 24576;                      \
            __builtin_amdgcn_global_load_lds(                                  \
                (const __attribute__((address_space(1))) void*)gk,             \
                (__attribute__((address_space(3))) void*)((sKd) +              \
                                                          (wave * 4 + i) * 512),\
                16, 0, 0);                                                     \
            __builtin_amdgcn_global_load_lds(                                  \
                (const __attribute__((address_space(1))) void*)(gV0 +          \
                                                               i * 32768),     \
                (__attribute__((address_space(3))) void*)((sVd) +              \
                                                          (wave * 4 + i) * 512),\
                16, 0, 0);                                                     \
        }                                                                      \
        gKe += 196608; gKo += 196608; gV0 += 64;                               \
    } while (0)

    unsigned short* pB = smem + 32768 + wave * 2048;

    floatx4 oacc[2][8] = {};
    float l_run[2] = {0.0f, 0.0f};

    STAGE_KT(smem, smem + 16384);
    asm volatile("s_waitcnt vmcnt(0)" ::: "memory");
    __builtin_amdgcn_s_barrier();
    asm volatile("" ::: "memory");

    for (int kt = 0; kt < 32; kt++) {
        const int cur = kt & 1;
        const unsigned short* sKc = smem + cur * 8192;
        const unsigned short* sVc = smem + 16384 + cur * 8192;
        if (kt < 31) {
            unsigned short* sKn = smem + (cur ^ 1) * 8192;
            unsigned short* sVn = smem + 16384 + (cur ^ 1) * 8192;
            STAGE_KT(sKn, sVn);
        }

        // ===== ks0: QK over kb=0,1 + softmax + P write (keys 0..31) =====
#pragma unroll
        for (int kb = 0; kb < 2; kb++) {
            floatx4 sacc[2] = {};
#pragma unroll
            for (int c = 0; c < 4; c++) {
                short8 kf = *(const short8*)(
                    sKc + (kb * 16 + l16) * 128 + (((c * 4 + lq) ^ (l16 & 7)) * 8));
#pragma unroll
                for (int qb = 0; qb < 2; qb++)
                    sacc[qb] = __builtin_amdgcn_mfma_f32_16x16x32_bf16(
                        kf, qf[qb][c], sacc[qb], 0, 0, 0);
            }
#pragma unroll
            for (int qb = 0; qb < 2; qb++) {
                float p0 = __builtin_exp2f(sacc[qb][0]);
                float p1 = __builtin_exp2f(sacc[qb][1]);
                float p2 = __builtin_exp2f(sacc[qb][2]);
                float p3 = __builtin_exp2f(sacc[qb][3]);
                l_run[qb] += (p0 + p1) + (p2 + p3);
                int row = qb * 16 + l16;
                uint2 u;
                u.x = pk_bf16(p0, p1);
                u.y = pk_bf16(p2, p3);
                *(uint2*)(pB + row * 64 +
                          (((kb * 2 + (lq >> 1)) ^ (row & 7)) * 8) +
                          (lq & 1) * 4) = u;
            }
        }
        asm volatile("s_waitcnt lgkmcnt(0)" ::: "memory");

        short8 pf0[2];
#pragma unroll
        for (int qb = 0; qb < 2; qb++) {
            int row = qb * 16 + l16;
            pf0[qb] = *(const short8*)(pB + row * 64 +
                                       ((lq ^ (row & 7)) * 8));
        }

        // ===== PV(ks0) =====
        __builtin_amdgcn_s_setprio(1);
#pragma unroll
        for (int nb = 0; nb < 8; nb++) {
            short8 vf = *(const short8*)(
                sVc + (nb * 16 + l16) * 64 + ((lq ^ (l16 & 7)) * 8));
#pragma unroll
            for (int qb = 0; qb < 2; qb++)
                oacc[qb][nb] = __builtin_amdgcn_mfma_f32_16x16x32_bf16(
                    vf, pf0[qb], oacc[qb][nb], 0, 0, 0);
        }
        __builtin_amdgcn_s_setprio(0);

        // ===== ks1: QK over kb=2,3 + softmax + P write (keys 32..63) =====
#pragma unroll
        for (int kb = 2; kb < 4; kb++) {
            floatx4 sacc[2] = {};
#pragma unroll
            for (int c = 0; c < 4; c++) {
                short8 kf = *(const short8*)(
                    sKc + (kb * 16 + l16) * 128 + (((c * 4 + lq) ^ (l16 & 7)) * 8));
#pragma unroll
                for (int qb = 0; qb < 2; qb++)
                    sacc[qb] = __builtin_amdgcn_mfma_f32_16x16x32_bf16(
                        kf, qf[qb][c], sacc[qb], 0, 0, 0);
            }
#pragma unroll
            for (int qb = 0; qb < 2; qb++) {
                float p0 = __builtin_exp2f(sacc[qb][0]);
                float p1 = __builtin_exp2f(sacc[qb][1]);
                float p2 = __builtin_exp2f(sacc[qb][2]);
                float p3 = __builtin_exp2f(sacc[qb][3]);
                l_run[qb] += (p0 + p1) + (p2 + p3);
                int row = qb * 16 + l16;
                uint2 u;
                u.x = pk_bf16(p0, p1);
                u.y = pk_bf16(p2, p3);
                *(uint2*)(pB + row * 64 +
                          (((kb * 2 + (lq >> 1)) ^ (row & 7)) * 8) +
                          (lq & 1) * 4) = u;
            }
        }
        asm volatile("s_waitcnt lgkmcnt(0)" ::: "memory");

        short8 pf1[2];
#pragma unroll
        for (int qb = 0; qb < 2; qb++) {
            int row = qb * 16 + l16;
            pf1[qb] = *(const short8*)(pB + row * 64 +
                                       (((4 + lq) ^ (row & 7)) * 8));
        }

        // ===== PV(ks1) =====
        __builtin_amdgcn_s_setprio(1);
#pragma unroll
        for (int nb = 0; nb < 8; nb++) {
            short8 vf = *(const short8*)(
                sVc + (nb * 16 + l16) * 64 + (((4 + lq) ^ (l16 & 7)) * 8));
#pragma unroll
            for (int qb = 0; qb < 2; qb++)
                oacc[qb][nb] = __builtin_amdgcn_mfma_f32_16x16x32_bf16(
                    vf, pf1[qb], oacc[qb][nb], 0, 0, 0);
        }
        __builtin_amdgcn_s_setprio(0);

        asm volatile("s_waitcnt vmcnt(0)" ::: "memory");
        __builtin_amdgcn_s_barrier();
        asm volatile("" ::: "memory");
    }
#undef STAGE_KT

#pragma unroll
    for (int qb = 0; qb < 2; qb++) {
        float l = l_run[qb];
        l += __shfl_xor(l, 16);
        l += __shfl_xor(l, 32);
        float inv = 1.0f / l;
        size_t row = (tokbase + qb * 16 + l16) * 2048 + h * 128;
#pragma unroll
        for (int nb = 0; nb < 8; nb++) {
            uint2 u;
            u.x = pk_bf16(oacc[qb][nb][0] * inv, oacc[qb][nb][1] * inv);
            u.y = pk_bf16(oacc[qb][nb][2] * inv, oacc[qb][nb][3] * inv);
            *(uint2*)(O + row + nb * 16 + lq * 4) = u;
        }
    }
}

// ---------------- launcher ----------------
extern "C" void kernel_launch(void* const* d_in, const int* in_sizes, int n_in,
                              void* d_out, int out_size, void* d_ws, size_t ws_size,
                              hipStream_t stream) {
    const float* x  = (const float*)d_in[0];
    const float* Wq = (const float*)d_in[1];
    const float* Wk = (const float*)d_in[2];
    const float* Wv = (const float*)d_in[3];
    const float* Wo = (const float*)d_in[4];

    char* ws = (char*)d_ws;
    unsigned short* x_bf   = (unsigned short*)(ws);               // 16 MB
    unsigned short* Wqk_bf = (unsigned short*)(ws + 16777216);    // 12 MB (Wq;Wk)
    unsigned short* Wv_bf  = (unsigned short*)(ws + 29360128);    // 4 MB
    unsigned short* Wo_bf  = (unsigned short*)(ws + 33554432);    // 8 MB
    unsigned short* QKb    = (unsigned short*)(ws + 41943040);    // 24 MB (4096x3072)
    unsigned short* Vtb    = (unsigned short*)(ws + 67108864);    // 8 MB  (1024x4096)
    unsigned short* Ob     = (unsigned short*)(ws + 75497472);    // 16 MB (4096x2048)

    cast_all_kernel<<<dim3(20480), 256, 0, stream>>>(
        x, Wq, Wk, Wv, Wo, x_bf, Wqk_bf, Wv_bf, Wo_bf);

    // QK = x @ [Wq;Wk]^T  and  Vt = Wv @ x^T (256 blocks = 1/CU, 512 thr)
    gemm_qkv_kernel<<<dim3(256), 512, 0, stream>>>(x_bf, Wqk_bf, Wv_bf, QKb, Vtb);

    // flash attention: 128 tokens/block
    flash_kernel<<<dim3(16, 32), 256, 0, stream>>>(QKb, Vtb, Ob);

    // out = O @ Wo^T : M=4096, N=2048, K=2048, fp32 out (256 blocks, 512 thr)
    gemm_o_kernel<<<dim3(256), 512, 0, stream>>>(Ob, Wo_bf, (float*)d_out);
}

// Round 11
// 311.706 us; speedup vs baseline: 1.0995x; 1.0062x over previous
//
#include <hip/hip_runtime.h>
#include <hip/hip_bf16.h>

typedef __attribute__((ext_vector_type(8))) short short8;
typedef __attribute__((ext_vector_type(4))) float floatx4;

__device__ inline unsigned short f2bf(float f) {
    unsigned int u = __float_as_uint(f);
    u += 0x7fffu + ((u >> 16) & 1u);           // round-to-nearest-even
    return (unsigned short)(u >> 16);
}

__device__ inline unsigned int pk_bf16(float lo, float hi) {
    __hip_bfloat162 h = __float22bfloat162_rn(float2{lo, hi});
    unsigned int u;
    __builtin_memcpy(&u, &h, 4);
    return u;
}

// ---------------- merged cast fp32 -> bf16 (all 5 tensors, one launch) -----
// Wq is pre-scaled by scale*log2(e) so flash computes exp2(q.k) directly.
__global__ void cast_all_kernel(const float* __restrict__ x,
                                const float* __restrict__ wq,
                                const float* __restrict__ wk,
                                const float* __restrict__ wv,
                                const float* __restrict__ wo,
                                unsigned short* __restrict__ xb,
                                unsigned short* __restrict__ wqkb,
                                unsigned short* __restrict__ wvb,
                                unsigned short* __restrict__ wob) {
    const float C2 = 0.08838834764831845f * 1.4426950408889634f;
    int bid = blockIdx.x;
    const float* src;
    unsigned short* dst;
    int base;
    float sc = 1.0f;
    if (bid < 8192)       { src = x;  dst = xb;             base = bid; }
    else if (bid < 12288) { src = wq; dst = wqkb;           base = bid - 8192; sc = C2; }
    else if (bid < 14336) { src = wk; dst = wqkb + 4194304; base = bid - 12288; }
    else if (bid < 16384) { src = wv; dst = wvb;            base = bid - 14336; }
    else                  { src = wo; dst = wob;            base = bid - 16384; }
    int i = base * 256 + threadIdx.x;   // float4 units
    float4 v = ((const float4*)src)[i];
    ushort4 o;
    o.x = f2bf(v.x * sc); o.y = f2bf(v.y * sc);
    o.z = f2bf(v.z * sc); o.w = f2bf(v.w * sc);
    ((ushort4*)dst)[i] = o;
}

// ---------------- 256x256 8-phase GEMM, race-hardened pipeline -------------
// (PROVEN r7/r8, best measured config.) Stage runs TWO K-tiles ahead, 4
// slots: iter t reads slot t&3, stages tile t+2 into slot of tile t-2
// (reads retired two top-barriers ago). Boundary wait = counted vmcnt(4)
// (retire tile t, keep t+1 in flight). Per tile 2 phases, each {ds_read ||
// stage -> barrier -> lgkmcnt(0) -> sched_barrier -> setprio(1) -> 16 MFMA}.
// Chunk = 16 rows x 32 cols (1KB): lane l -> row c*16+(l>>2), lds k-slot l&3
// holds global k-chunk (l&3)^(row&3); frag read slot = lq^(l16&3).
// NOTE r10: XCD swizzle measured <=0 here — inputs are L3-resident (32 MB),
// so T1's HBM-refetch mechanism has nothing to save. Keep linear blockIdx.
template <int OUT_BF16>
__device__ __forceinline__ void gemm256_body(
        const unsigned short* __restrict__ A,
        const unsigned short* __restrict__ B,
        void* __restrict__ Cp, int ldc, int m0, int n0,
        unsigned short* sL) {
    const int tid  = threadIdx.x;
    const int wave = tid >> 6;
    const int lane = tid & 63;
    const int l16  = lane & 15;
    const int lq   = lane >> 4;
    const int wm   = (wave >> 2) * 128;
    const int wn   = (wave & 3) * 64;
    const int kx   = lq ^ (l16 & 3);

    floatx4 acc[8][4] = {};

    const unsigned short* gA[2];
    const unsigned short* gB[2];
#pragma unroll
    for (int i = 0; i < 2; i++) {
        int c   = wave * 2 + i;
        int row = c * 16 + (lane >> 2);
        int g   = (lane & 3) ^ (row & 3);
        gA[i] = A + (size_t)(m0 + row) * 2048 + g * 8;
        gB[i] = B + (size_t)(n0 + row) * 2048 + g * 8;
    }

#define STG_A32(slot)                                                          \
    do {                                                                       \
        _Pragma("unroll")                                                      \
        for (int i = 0; i < 2; i++) {                                          \
            __builtin_amdgcn_global_load_lds(                                  \
                (const __attribute__((address_space(1))) void*)gA[i],          \
                (__attribute__((address_space(3))) void*)(sL + (slot) * 16384 +\
                                                          (wave * 2 + i) * 512),\
                16, 0, 0);                                                     \
            gA[i] += 32;                                                       \
        }                                                                      \
    } while (0)
#define STG_B32(slot)                                                          \
    do {                                                                       \
        _Pragma("unroll")                                                      \
        for (int i = 0; i < 2; i++) {                                          \
            __builtin_amdgcn_global_load_lds(                                  \
                (const __attribute__((address_space(1))) void*)gB[i],          \
                (__attribute__((address_space(3))) void*)(sL + (slot) * 16384 +\
                                                  8192 + (wave * 2 + i) * 512),\
                16, 0, 0);                                                     \
            gB[i] += 32;                                                       \
        }                                                                      \
    } while (0)

    // prologue: stage tiles 0,1 into slots 0,1 (8 loads/wave in flight)
    STG_A32(0); STG_B32(0);
    STG_A32(1); STG_B32(1);

    for (int t = 0; t < 64; t++) {
        const int sc = t & 3;
        const int sn = (t + 2) & 3;        // slot of tile t-2 (retired reads)
        // boundary: retire tile t's 4 loads; tile t+1 stays in flight
        if (t < 63) asm volatile("s_waitcnt vmcnt(4)" ::: "memory");
        else        asm volatile("s_waitcnt vmcnt(0)" ::: "memory");
        __builtin_amdgcn_s_barrier();
        asm volatile("" ::: "memory");

        const unsigned short* sAc = sL + sc * 16384;
        const unsigned short* sBc = sAc + 8192;
        short8 af[4], bf[4];

        // ---- phase 0: mh0 (mb 0-3) ----
#pragma unroll
        for (int mb = 0; mb < 4; mb++)
            af[mb] = *(const short8*)(sAc + (wm + mb * 16 + l16) * 32 + kx * 8);
#pragma unroll
        for (int nb = 0; nb < 4; nb++)
            bf[nb] = *(const short8*)(sBc + (wn + nb * 16 + l16) * 32 + kx * 8);
        if (t < 62) STG_A32(sn);
        __builtin_amdgcn_s_barrier();
        asm volatile("s_waitcnt lgkmcnt(0)" ::: "memory");
        __builtin_amdgcn_sched_barrier(0);
        __builtin_amdgcn_s_setprio(1);
#pragma unroll
        for (int mb = 0; mb < 4; mb++)
#pragma unroll
            for (int nb = 0; nb < 4; nb++)
                acc[mb][nb] = __builtin_amdgcn_mfma_f32_16x16x32_bf16(
                    af[mb], bf[nb], acc[mb][nb], 0, 0, 0);
        __builtin_amdgcn_s_setprio(0);
        __builtin_amdgcn_s_barrier();
        asm volatile("" ::: "memory");

        // ---- phase 1: mh1 (mb 4-7), bf reused from registers ----
#pragma unroll
        for (int mb = 0; mb < 4; mb++)
            af[mb] = *(const short8*)(sAc + (wm + 64 + mb * 16 + l16) * 32 + kx * 8);
        if (t < 62) STG_B32(sn);
        __builtin_amdgcn_s_barrier();
        asm volatile("s_waitcnt lgkmcnt(0)" ::: "memory");
        __builtin_amdgcn_sched_barrier(0);
        __builtin_amdgcn_s_setprio(1);
#pragma unroll
        for (int mb = 0; mb < 4; mb++)
#pragma unroll
            for (int nb = 0; nb < 4; nb++)
                acc[4 + mb][nb] = __builtin_amdgcn_mfma_f32_16x16x32_bf16(
                    af[mb], bf[nb], acc[4 + mb][nb], 0, 0, 0);
        __builtin_amdgcn_s_setprio(0);
        // tile closed by next iteration's vmcnt + barrier
    }
#undef STG_A32
#undef STG_B32

#pragma unroll
    for (int mb = 0; mb < 8; mb++)
#pragma unroll
        for (int nb = 0; nb < 4; nb++)
#pragma unroll
            for (int r = 0; r < 4; r++) {
                int row = m0 + wm + mb * 16 + lq * 4 + r;
                int col = n0 + wn + nb * 16 + l16;
                if (OUT_BF16)
                    ((unsigned short*)Cp)[(size_t)row * ldc + col] = f2bf(acc[mb][nb][r]);
                else
                    ((float*)Cp)[(size_t)row * ldc + col] = acc[mb][nb][r];
            }
}

// ---------------- 128x256 single-phase variant (same hardened pipeline) ----
// (PROVEN r8.) 256 blocks = 1/CU for gemm_o. One phase/tile; counted
// vmcnt(3); stage 2 ahead into slot of tile t-2; 4 slots x 24 KB = 96 KB.
template <int OUT_BF16>
__device__ __forceinline__ void gemm128_body(
        const unsigned short* __restrict__ A,
        const unsigned short* __restrict__ B,
        void* __restrict__ Cp, int ldc, int m0, int n0,
        unsigned short* sL) {
    const int tid  = threadIdx.x;
    const int wave = tid >> 6;
    const int lane = tid & 63;
    const int l16  = lane & 15;
    const int lq   = lane >> 4;
    const int wm   = (wave >> 2) * 64;
    const int wn   = (wave & 3) * 64;
    const int kx   = lq ^ (l16 & 3);

    floatx4 acc[4][4] = {};

    const unsigned short* gA0;
    const unsigned short* gB[2];
    {
        int row = wave * 16 + (lane >> 2);              // A chunk = wave
        int g   = (lane & 3) ^ (row & 3);
        gA0 = A + (size_t)(m0 + row) * 2048 + g * 8;
    }
#pragma unroll
    for (int i = 0; i < 2; i++) {
        int c   = wave * 2 + i;                         // B chunks
        int row = c * 16 + (lane >> 2);
        int g   = (lane & 3) ^ (row & 3);
        gB[i] = B + (size_t)(n0 + row) * 2048 + g * 8;
    }

#define STG_O(slot)                                                            \
    do {                                                                       \
        __builtin_amdgcn_global_load_lds(                                      \
            (const __attribute__((address_space(1))) void*)gA0,                \
            (__attribute__((address_space(3))) void*)(sL + (slot) * 12288 +    \
                                                      wave * 512),             \
            16, 0, 0);                                                         \
        gA0 += 32;                                                             \
        _Pragma("unroll")                                                      \
        for (int i = 0; i < 2; i++) {                                          \
            __builtin_amdgcn_global_load_lds(                                  \
                (const __attribute__((address_space(1))) void*)gB[i],          \
                (__attribute__((address_space(3))) void*)(sL + (slot) * 12288 +\
                                                  4096 + (wave * 2 + i) * 512),\
                16, 0, 0);                                                     \
            gB[i] += 32;                                                       \
        }                                                                      \
    } while (0)

    // prologue: stage tiles 0,1 into slots 0,1 (6 loads/wave in flight)
    STG_O(0); STG_O(1);

    for (int t = 0; t < 64; t++) {
        const int sc = t & 3;
        const int sn = (t + 2) & 3;        // slot of tile t-2 (retired reads)
        if (t < 63) asm volatile("s_waitcnt vmcnt(3)" ::: "memory");
        else        asm volatile("s_waitcnt vmcnt(0)" ::: "memory");
        __builtin_amdgcn_s_barrier();
        asm volatile("" ::: "memory");

        const unsigned short* sAc = sL + sc * 12288;
        const unsigned short* sBc = sAc + 4096;
        short8 af[4], bf[4];
#pragma unroll
        for (int mb = 0; mb < 4; mb++)
            af[mb] = *(const short8*)(sAc + (wm + mb * 16 + l16) * 32 + kx * 8);
#pragma unroll
        for (int nb = 0; nb < 4; nb++)
            bf[nb] = *(const short8*)(sBc + (wn + nb * 16 + l16) * 32 + kx * 8);
        if (t < 62) STG_O(sn);
        __builtin_amdgcn_s_barrier();
        asm volatile("s_waitcnt lgkmcnt(0)" ::: "memory");
        __builtin_amdgcn_sched_barrier(0);
        __builtin_amdgcn_s_setprio(1);
#pragma unroll
        for (int mb = 0; mb < 4; mb++)
#pragma unroll
            for (int nb = 0; nb < 4; nb++)
                acc[mb][nb] = __builtin_amdgcn_mfma_f32_16x16x32_bf16(
                    af[mb], bf[nb], acc[mb][nb], 0, 0, 0);
        __builtin_amdgcn_s_setprio(0);
        // tile closed by next iteration's vmcnt + barrier
    }
#undef STG_O

#pragma unroll
    for (int mb = 0; mb < 4; mb++)
#pragma unroll
        for (int nb = 0; nb < 4; nb++)
#pragma unroll
            for (int r = 0; r < 4; r++) {
                int row = m0 + wm + mb * 16 + lq * 4 + r;
                int col = n0 + wn + nb * 16 + l16;
                if (OUT_BF16)
                    ((unsigned short*)Cp)[(size_t)row * ldc + col] = f2bf(acc[mb][nb][r]);
                else
                    ((float*)Cp)[(size_t)row * ldc + col] = acc[mb][nb][r];
            }
}

// ---------------- merged QK + Vt gemm (256 blocks = 1/CU) ------------------
__global__ __launch_bounds__(512, 1) void gemm_qkv_kernel(
        const unsigned short* __restrict__ x_bf,
        const unsigned short* __restrict__ Wqk,
        const unsigned short* __restrict__ Wv,
        unsigned short* __restrict__ QKb,
        unsigned short* __restrict__ Vtb) {
    __shared__ __align__(16) unsigned short sL[4 * 16384];   // 128 KB
    const int bid = blockIdx.x;
    if (bid < 192) {
        // QK = x @ [Wq;Wk]^T : M=4096 N=3072 (16 x 12 tiles of 256)
        gemm256_body<1>(x_bf, Wqk, QKb, 3072,
                        (bid / 12) * 256, (bid % 12) * 256, sL);
    } else {
        // Vt = Wv @ x^T : M=1024 N=4096 (4 x 16 tiles of 256)
        int t = bid - 192;
        gemm256_body<1>(Wv, x_bf, Vtb, 4096,
                        (t / 16) * 256, (t % 16) * 256, sL);
    }
}

// ---------------- O-proj gemm (fp32 out, 256 blocks = 1/CU) ----------------
__global__ __launch_bounds__(512, 1) void gemm_o_kernel(
        const unsigned short* __restrict__ A,
        const unsigned short* __restrict__ B,
        float* __restrict__ C) {
    __shared__ __align__(16) unsigned short sL[4 * 12288];   // 96 KB
    gemm128_body<0>(A, B, C, 2048,
                    blockIdx.y * 128, blockIdx.x * 256, sL);
}

// ---------------- flash attention v4 (proven plateau: ~99 us) ---------------
// Six structural variants (r0-r9) all land 99-112 us; this is the best.
// 4 waves = 4 q-slices (32 q-rows each), all 64 keys/wave; double-buffered
// sK/sV + wave-private sP (80 KB, 2 blocks/CU — grid 512 caps at 2/CU
// anyway, so LDS is free); two 32-key PV steps interleave with QK/softmax.
__global__ __launch_bounds__(256, 2) void flash_kernel(
        const unsigned short* __restrict__ QK,
        const unsigned short* __restrict__ Vt,
        unsigned short* __restrict__ O) {
    // layout (ushorts): sK[2][8192] @0, sV[2][8192] @16384, sP[4][2048] @32768
    __shared__ __align__(16) unsigned short smem[40960];

    const int tid  = threadIdx.x;
    const int wave = tid >> 6;
    const int lane = tid & 63;
    const int l16  = lane & 15;
    const int lq   = lane >> 4;
    const int qt   = blockIdx.x;          // 0..15 (128 tokens each)
    const int bh   = blockIdx.y;
    const int b    = bh >> 4;
    const int h    = bh & 15;
    const int kvh  = h >> 1;
    const size_t tokbase = (size_t)b * 2048 + qt * 128 + wave * 32;

    // Q fragments: 32 rows x 128 d per wave (B-operand, col = q = l16)
    short8 qf[2][4];
#pragma unroll
    for (int qb = 0; qb < 2; qb++) {
        const unsigned short* qp =
            QK + (tokbase + qb * 16 + l16) * 3072 + h * 128 + lq * 8;
#pragma unroll
        for (int c = 0; c < 4; c++) qf[qb][c] = *(const short8*)(qp + c * 32);
    }

    const unsigned short* gKe =
        QK + ((size_t)b * 2048 + wave * 16 + lq) * 3072 + 2048 + kvh * 128 +
        (l16 ^ lq) * 8;
    const unsigned short* gKo =
        QK + ((size_t)b * 2048 + wave * 16 + 4 + lq) * 3072 + 2048 + kvh * 128 +
        (l16 ^ (lq + 4)) * 8;
    const unsigned short* gV0 =
        Vt + (size_t)(kvh * 128 + wave * 32 + (lane >> 3)) * 4096 +
        (size_t)b * 2048 + ((lane & 7) ^ (lane >> 3)) * 8;

#define STAGE_KT(sKd, sVd)                                                     \
    do {                                                                       \
        _Pragma("unroll")                                                      \
        for (int i = 0; i < 4; i++) {                                          \
            const unsigned short* gk =                                         \
                ((i & 1) ? gKo : gKe) + (i >> 1) * 24576;                      \
            __builtin_amdgcn_global_load_lds(                                  \
                (const __attribute__((address_space(1))) void*)gk,             \
                (__attribute__((address_space(3))) void*)((sKd) +              \
                                                          (wave * 4 + i) * 512),\
                16, 0, 0);                                                     \
            __builtin_amdgcn_global_load_lds(                                  \
                (const __attribute__((address_space(1))) void*)(gV0 +          \
                                                               i * 32768),     \
                (__attribute__((address_space(3))) void*)((sVd) +              \
                                                          (wave * 4 + i) * 512),\
                16, 0, 0);                                                     \
        }                                                                      \
        gKe += 196608; gKo += 196608; gV0 += 64;                               \
    } while (0)

    unsigned short* pB = smem + 32768 + wave * 2048;

    floatx4 oacc[2][8] = {};
    float l_run[2] = {0.0f, 0.0f};

    STAGE_KT(smem, smem + 16384);
    asm volatile("s_waitcnt vmcnt(0)" ::: "memory");
    __builtin_amdgcn_s_barrier();
    asm volatile("" ::: "memory");

    for (int kt = 0; kt < 32; kt++) {
        const int cur = kt & 1;
        const unsigned short* sKc = smem + cur * 8192;
        const unsigned short* sVc = smem + 16384 + cur * 8192;
        if (kt < 31) {
            unsigned short* sKn = smem + (cur ^ 1) * 8192;
            unsigned short* sVn = smem + 16384 + (cur ^ 1) * 8192;
            STAGE_KT(sKn, sVn);
        }

        // ===== ks0: QK over kb=0,1 + softmax + P write (keys 0..31) =====
#pragma unroll
        for (int kb = 0; kb < 2; kb++) {
            floatx4 sacc[2] = {};
#pragma unroll
            for (int c = 0; c < 4; c++) {
                short8 kf = *(const short8*)(
                    sKc + (kb * 16 + l16) * 128 + (((c * 4 + lq) ^ (l16 & 7)) * 8));
#pragma unroll
                for (int qb = 0; qb < 2; qb++)
                    sacc[qb] = __builtin_amdgcn_mfma_f32_16x16x32_bf16(
                        kf, qf[qb][c], sacc[qb], 0, 0, 0);
            }
#pragma unroll
            for (int qb = 0; qb < 2; qb++) {
                float p0 = __builtin_exp2f(sacc[qb][0]);
                float p1 = __builtin_exp2f(sacc[qb][1]);
                float p2 = __builtin_exp2f(sacc[qb][2]);
                float p3 = __builtin_exp2f(sacc[qb][3]);
                l_run[qb] += (p0 + p1) + (p2 + p3);
                int row = qb * 16 + l16;
                uint2 u;
                u.x = pk_bf16(p0, p1);
                u.y = pk_bf16(p2, p3);
                *(uint2*)(pB + row * 64 +
                          (((kb * 2 + (lq >> 1)) ^ (row & 7)) * 8) +
                          (lq & 1) * 4) = u;
            }
        }
        asm volatile("s_waitcnt lgkmcnt(0)" ::: "memory");

        short8 pf0[2];
#pragma unroll
        for (int qb = 0; qb < 2; qb++) {
            int row = qb * 16 + l16;
            pf0[qb] = *(const short8*)(pB + row * 64 +
                                       ((lq ^ (row & 7)) * 8));
        }

        // ===== PV(ks0) =====
        __builtin_amdgcn_s_setprio(1);
#pragma unroll
        for (int nb = 0; nb < 8; nb++) {
            short8 vf = *(const short8*)(
                sVc + (nb * 16 + l16) * 64 + ((lq ^ (l16 & 7)) * 8));
#pragma unroll
            for (int qb = 0; qb < 2; qb++)
                oacc[qb][nb] = __builtin_amdgcn_mfma_f32_16x16x32_bf16(
                    vf, pf0[qb], oacc[qb][nb], 0, 0, 0);
        }
        __builtin_amdgcn_s_setprio(0);

        // ===== ks1: QK over kb=2,3 + softmax + P write (keys 32..63) =====
#pragma unroll
        for (int kb = 2; kb < 4; kb++) {
            floatx4 sacc[2] = {};
#pragma unroll
            for (int c = 0; c < 4; c++) {
                short8 kf = *(const short8*)(
                    sKc + (kb * 16 + l16) * 128 + (((c * 4 + lq) ^ (l16 & 7)) * 8));
#pragma unroll
                for (int qb = 0; qb < 2; qb++)
                    sacc[qb] = __builtin_amdgcn_mfma_f32_16x16x32_bf16(
                        kf, qf[qb][c], sacc[qb], 0, 0, 0);
            }
#pragma unroll
            for (int qb = 0; qb < 2; qb++) {
                float p0 = __builtin_exp2f(sacc[qb][0]);
                float p1 = __builtin_exp2f(sacc[qb][1]);
                float p2 = __builtin_exp2f(sacc[qb][2]);
                float p3 = __builtin_exp2f(sacc[qb][3]);
                l_run[qb] += (p0 + p1) + (p2 + p3);
                int row = qb * 16 + l16;
                uint2 u;
                u.x = pk_bf16(p0, p1);
                u.y = pk_bf16(p2, p3);
                *(uint2*)(pB + row * 64 +
                          (((kb * 2 + (lq >> 1)) ^ (row & 7)) * 8) +
                          (lq & 1) * 4) = u;
            }
        }
        asm volatile("s_waitcnt lgkmcnt(0)" ::: "memory");

        short8 pf1[2];
#pragma unroll
        for (int qb = 0; qb < 2; qb++) {
            int row = qb * 16 + l16;
            pf1[qb] = *(const short8*)(pB + row * 64 +
                                       (((4 + lq) ^ (row & 7)) * 8));
        }

        // ===== PV(ks1) =====
        __builtin_amdgcn_s_setprio(1);
#pragma unroll
        for (int nb = 0; nb < 8; nb++) {
            short8 vf = *(const short8*)(
                sVc + (nb * 16 + l16) * 64 + (((4 + lq) ^ (l16 & 7)) * 8));
#pragma unroll
            for (int qb = 0; qb < 2; qb++)
                oacc[qb][nb] = __builtin_amdgcn_mfma_f32_16x16x32_bf16(
                    vf, pf1[qb], oacc[qb][nb], 0, 0, 0);
        }
        __builtin_amdgcn_s_setprio(0);

        asm volatile("s_waitcnt vmcnt(0)" ::: "memory");
        __builtin_amdgcn_s_barrier();
        asm volatile("" ::: "memory");
    }
#undef STAGE_KT

#pragma unroll
    for (int qb = 0; qb < 2; qb++) {
        float l = l_run[qb];
        l += __shfl_xor(l, 16);
        l += __shfl_xor(l, 32);
        float inv = 1.0f / l;
        size_t row = (tokbase + qb * 16 + l16) * 2048 + h * 128;
#pragma unroll
        for (int nb = 0; nb < 8; nb++) {
            uint2 u;
            u.x = pk_bf16(oacc[qb][nb][0] * inv, oacc[qb][nb][1] * inv);
            u.y = pk_bf16(oacc[qb][nb][2] * inv, oacc[qb][nb][3] * inv);
            *(uint2*)(O + row + nb * 16 + lq * 4) = u;
        }
    }
}

// ---------------- launcher ----------------
extern "C" void kernel_launch(void* const* d_in, const int* in_sizes, int n_in,
                              void* d_out, int out_size, void* d_ws, size_t ws_size,
                              hipStream_t stream) {
    const float* x  = (const float*)d_in[0];
    const float* Wq = (const float*)d_in[1];
    const float* Wk = (const float*)d_in[2];
    const float* Wv = (const float*)d_in[3];
    const float* Wo = (const float*)d_in[4];

    char* ws = (char*)d_ws;
    unsigned short* x_bf   = (unsigned short*)(ws);               // 16 MB
    unsigned short* Wqk_bf = (unsigned short*)(ws + 16777216);    // 12 MB (Wq;Wk)
    unsigned short* Wv_bf  = (unsigned short*)(ws + 29360128);    // 4 MB
    unsigned short* Wo_bf  = (unsigned short*)(ws + 33554432);    // 8 MB
    unsigned short* QKb    = (unsigned short*)(ws + 41943040);    // 24 MB (4096x3072)
    unsigned short* Vtb    = (unsigned short*)(ws + 67108864);    // 8 MB  (1024x4096)
    unsigned short* Ob     = (unsigned short*)(ws + 75497472);    // 16 MB (4096x2048)

    cast_all_kernel<<<dim3(20480), 256, 0, stream>>>(
        x, Wq, Wk, Wv, Wo, x_bf, Wqk_bf, Wv_bf, Wo_bf);

    // QK = x @ [Wq;Wk]^T  and  Vt = Wv @ x^T (256 blocks = 1/CU, 512 thr)
    gemm_qkv_kernel<<<dim3(256), 512, 0, stream>>>(x_bf, Wqk_bf, Wv_bf, QKb, Vtb);

    // flash attention: 128 tokens/block
    flash_kernel<<<dim3(16, 32), 256, 0, stream>>>(QKb, Vtb, Ob);

    // out = O @ Wo^T : M=4096, N=2048, K=2048, fp32 out (32 x 8 tiles)
    gemm_o_kernel<<<dim3(8, 32), 512, 0, stream>>>(Ob, Wo_bf, (float*)d_out);
}

// Round 12
// 308.351 us; speedup vs baseline: 1.1115x; 1.0109x over previous
//
#include <hip/hip_runtime.h>
#include <hip/hip_bf16.h>

typedef __attribute__((ext_vector_type(8))) short short8;
typedef __attribute__((ext_vector_type(4))) float floatx4;

__device__ inline unsigned short f2bf(float f) {
    unsigned int u = __float_as_uint(f);
    u += 0x7fffu + ((u >> 16) & 1u);           // round-to-nearest-even
    return (unsigned short)(u >> 16);
}

__device__ inline unsigned int pk_bf16(float lo, float hi) {
    __hip_bfloat162 h = __float22bfloat162_rn(float2{lo, hi});
    unsigned int u;
    __builtin_memcpy(&u, &h, 4);
    return u;
}

// ---------------- merged cast fp32 -> bf16 (all 5 tensors, one launch) -----
// Wq is pre-scaled by scale*log2(e) so flash computes exp2(q.k) directly.
__global__ void cast_all_kernel(const float* __restrict__ x,
                                const float* __restrict__ wq,
                                const float* __restrict__ wk,
                                const float* __restrict__ wv,
                                const float* __restrict__ wo,
                                unsigned short* __restrict__ xb,
                                unsigned short* __restrict__ wqkb,
                                unsigned short* __restrict__ wvb,
                                unsigned short* __restrict__ wob) {
    const float C2 = 0.08838834764831845f * 1.4426950408889634f;
    int bid = blockIdx.x;
    const float* src;
    unsigned short* dst;
    int base;
    float sc = 1.0f;
    if (bid < 8192)       { src = x;  dst = xb;             base = bid; }
    else if (bid < 12288) { src = wq; dst = wqkb;           base = bid - 8192; sc = C2; }
    else if (bid < 14336) { src = wk; dst = wqkb + 4194304; base = bid - 12288; }
    else if (bid < 16384) { src = wv; dst = wvb;            base = bid - 14336; }
    else                  { src = wo; dst = wob;            base = bid - 16384; }
    int i = base * 256 + threadIdx.x;   // float4 units
    float4 v = ((const float4*)src)[i];
    ushort4 o;
    o.x = f2bf(v.x * sc); o.y = f2bf(v.y * sc);
    o.z = f2bf(v.z * sc); o.w = f2bf(v.w * sc);
    ((ushort4*)dst)[i] = o;
}

// ---------------- 256x256 GEMM, hardened pipeline, de-barriered tile -------
// Cross-wave sync (UNCHANGED from proven r7/r8): stage runs TWO K-tiles
// ahead, 4 slots; iter t reads slot t&3, stages tile t+2 into slot of tile
// t-2 (that slot's reads retired before two top-barriers: each wave's
// ds_reads drain before its MFMA uses, hence before its next top barrier).
// Boundary wait = counted vmcnt(4) — invariant is position-independent
// within the body (8 loads outstanding at each top; retire oldest 4).
// NEW r12: mid-tile barriers + forced lgkmcnt(0)+sched_barrier removed —
// they were wave-LOCAL scheduling scaffolding (4 lockstep points/tile)
// that serialized ds_read vs MFMA. Now: all 12 ds_reads issued up front,
// both stage calls, then the 32-MFMA cluster under setprio; the compiler's
// own fine-grained lgkmcnt(N) interleaves reads with MFMAs (m97 behavior).
// Chunk = 16 rows x 32 cols (1KB): lane l -> row c*16+(l>>2), lds k-slot l&3
// holds global k-chunk (l&3)^(row&3); frag read slot = lq^(l16&3).
template <int OUT_BF16>
__device__ __forceinline__ void gemm256_body(
        const unsigned short* __restrict__ A,
        const unsigned short* __restrict__ B,
        void* __restrict__ Cp, int ldc, int m0, int n0,
        unsigned short* sL) {
    const int tid  = threadIdx.x;
    const int wave = tid >> 6;
    const int lane = tid & 63;
    const int l16  = lane & 15;
    const int lq   = lane >> 4;
    const int wm   = (wave >> 2) * 128;
    const int wn   = (wave & 3) * 64;
    const int kx   = lq ^ (l16 & 3);

    floatx4 acc[8][4] = {};

    const unsigned short* gA[2];
    const unsigned short* gB[2];
#pragma unroll
    for (int i = 0; i < 2; i++) {
        int c   = wave * 2 + i;
        int row = c * 16 + (lane >> 2);
        int g   = (lane & 3) ^ (row & 3);
        gA[i] = A + (size_t)(m0 + row) * 2048 + g * 8;
        gB[i] = B + (size_t)(n0 + row) * 2048 + g * 8;
    }

#define STG_A32(slot)                                                          \
    do {                                                                       \
        _Pragma("unroll")                                                      \
        for (int i = 0; i < 2; i++) {                                          \
            __builtin_amdgcn_global_load_lds(                                  \
                (const __attribute__((address_space(1))) void*)gA[i],          \
                (__attribute__((address_space(3))) void*)(sL + (slot) * 16384 +\
                                                          (wave * 2 + i) * 512),\
                16, 0, 0);                                                     \
            gA[i] += 32;                                                       \
        }                                                                      \
    } while (0)
#define STG_B32(slot)                                                          \
    do {                                                                       \
        _Pragma("unroll")                                                      \
        for (int i = 0; i < 2; i++) {                                          \
            __builtin_amdgcn_global_load_lds(                                  \
                (const __attribute__((address_space(1))) void*)gB[i],          \
                (__attribute__((address_space(3))) void*)(sL + (slot) * 16384 +\
                                                  8192 + (wave * 2 + i) * 512),\
                16, 0, 0);                                                     \
            gB[i] += 32;                                                       \
        }                                                                      \
    } while (0)

    // prologue: stage tiles 0,1 into slots 0,1 (8 loads/wave in flight)
    STG_A32(0); STG_B32(0);
    STG_A32(1); STG_B32(1);

    for (int t = 0; t < 64; t++) {
        const int sc = t & 3;
        const int sn = (t + 2) & 3;        // slot of tile t-2 (retired reads)
        // boundary: retire tile t's 4 loads; tile t+1 stays in flight
        if (t < 63) asm volatile("s_waitcnt vmcnt(4)" ::: "memory");
        else        asm volatile("s_waitcnt vmcnt(0)" ::: "memory");
        __builtin_amdgcn_s_barrier();
        asm volatile("" ::: "memory");

        const unsigned short* sAc = sL + sc * 16384;
        const unsigned short* sBc = sAc + 8192;
        short8 af0[4], af1[4], bf[4];
#pragma unroll
        for (int mb = 0; mb < 4; mb++)
            af0[mb] = *(const short8*)(sAc + (wm + mb * 16 + l16) * 32 + kx * 8);
#pragma unroll
        for (int nb = 0; nb < 4; nb++)
            bf[nb] = *(const short8*)(sBc + (wn + nb * 16 + l16) * 32 + kx * 8);
#pragma unroll
        for (int mb = 0; mb < 4; mb++)
            af1[mb] = *(const short8*)(sAc + (wm + 64 + mb * 16 + l16) * 32 + kx * 8);
        if (t < 62) { STG_A32(sn); STG_B32(sn); }
        __builtin_amdgcn_s_setprio(1);
#pragma unroll
        for (int mb = 0; mb < 4; mb++)
#pragma unroll
            for (int nb = 0; nb < 4; nb++)
                acc[mb][nb] = __builtin_amdgcn_mfma_f32_16x16x32_bf16(
                    af0[mb], bf[nb], acc[mb][nb], 0, 0, 0);
#pragma unroll
        for (int mb = 0; mb < 4; mb++)
#pragma unroll
            for (int nb = 0; nb < 4; nb++)
                acc[4 + mb][nb] = __builtin_amdgcn_mfma_f32_16x16x32_bf16(
                    af1[mb], bf[nb], acc[4 + mb][nb], 0, 0, 0);
        __builtin_amdgcn_s_setprio(0);
        // tile closed by next iteration's vmcnt + barrier
    }
#undef STG_A32
#undef STG_B32

#pragma unroll
    for (int mb = 0; mb < 8; mb++)
#pragma unroll
        for (int nb = 0; nb < 4; nb++)
#pragma unroll
            for (int r = 0; r < 4; r++) {
                int row = m0 + wm + mb * 16 + lq * 4 + r;
                int col = n0 + wn + nb * 16 + l16;
                if (OUT_BF16)
                    ((unsigned short*)Cp)[(size_t)row * ldc + col] = f2bf(acc[mb][nb][r]);
                else
                    ((float*)Cp)[(size_t)row * ldc + col] = acc[mb][nb][r];
            }
}

// ---------------- 128x256 variant (same hardened pipeline, de-barriered) ---
// 256 blocks = 1/CU for gemm_o. Counted vmcnt(3); stage 2 ahead into slot
// of tile t-2; 4 slots x 24 KB = 96 KB. Mid-tile barrier removed (r12).
template <int OUT_BF16>
__device__ __forceinline__ void gemm128_body(
        const unsigned short* __restrict__ A,
        const unsigned short* __restrict__ B,
        void* __restrict__ Cp, int ldc, int m0, int n0,
        unsigned short* sL) {
    const int tid  = threadIdx.x;
    const int wave = tid >> 6;
    const int lane = tid & 63;
    const int l16  = lane & 15;
    const int lq   = lane >> 4;
    const int wm   = (wave >> 2) * 64;
    const int wn   = (wave & 3) * 64;
    const int kx   = lq ^ (l16 & 3);

    floatx4 acc[4][4] = {};

    const unsigned short* gA0;
    const unsigned short* gB[2];
    {
        int row = wave * 16 + (lane >> 2);              // A chunk = wave
        int g   = (lane & 3) ^ (row & 3);
        gA0 = A + (size_t)(m0 + row) * 2048 + g * 8;
    }
#pragma unroll
    for (int i = 0; i < 2; i++) {
        int c   = wave * 2 + i;                         // B chunks
        int row = c * 16 + (lane >> 2);
        int g   = (lane & 3) ^ (row & 3);
        gB[i] = B + (size_t)(n0 + row) * 2048 + g * 8;
    }

#define STG_O(slot)                                                            \
    do {                                                                       \
        __builtin_amdgcn_global_load_lds(                                      \
            (const __attribute__((address_space(1))) void*)gA0,                \
            (__attribute__((address_space(3))) void*)(sL + (slot) * 12288 +    \
                                                      wave * 512),             \
            16, 0, 0);                                                         \
        gA0 += 32;                                                             \
        _Pragma("unroll")                                                      \
        for (int i = 0; i < 2; i++) {                                          \
            __builtin_amdgcn_global_load_lds(                                  \
                (const __attribute__((address_space(1))) void*)gB[i],          \
                (__attribute__((address_space(3))) void*)(sL + (slot) * 12288 +\
                                                  4096 + (wave * 2 + i) * 512),\
                16, 0, 0);                                                     \
            gB[i] += 32;                                                       \
        }                                                                      \
    } while (0)

    // prologue: stage tiles 0,1 into slots 0,1 (6 loads/wave in flight)
    STG_O(0); STG_O(1);

    for (int t = 0; t < 64; t++) {
        const int sc = t & 3;
        const int sn = (t + 2) & 3;        // slot of tile t-2 (retired reads)
        if (t < 63) asm volatile("s_waitcnt vmcnt(3)" ::: "memory");
        else        asm volatile("s_waitcnt vmcnt(0)" ::: "memory");
        __builtin_amdgcn_s_barrier();
        asm volatile("" ::: "memory");

        const unsigned short* sAc = sL + sc * 12288;
        const unsigned short* sBc = sAc + 4096;
        short8 af[4], bf[4];
#pragma unroll
        for (int mb = 0; mb < 4; mb++)
            af[mb] = *(const short8*)(sAc + (wm + mb * 16 + l16) * 32 + kx * 8);
#pragma unroll
        for (int nb = 0; nb < 4; nb++)
            bf[nb] = *(const short8*)(sBc + (wn + nb * 16 + l16) * 32 + kx * 8);
        if (t < 62) STG_O(sn);
        __builtin_amdgcn_s_setprio(1);
#pragma unroll
        for (int mb = 0; mb < 4; mb++)
#pragma unroll
            for (int nb = 0; nb < 4; nb++)
                acc[mb][nb] = __builtin_amdgcn_mfma_f32_16x16x32_bf16(
                    af[mb], bf[nb], acc[mb][nb], 0, 0, 0);
        __builtin_amdgcn_s_setprio(0);
        // tile closed by next iteration's vmcnt + barrier
    }
#undef STG_O

#pragma unroll
    for (int mb = 0; mb < 4; mb++)
#pragma unroll
        for (int nb = 0; nb < 4; nb++)
#pragma unroll
            for (int r = 0; r < 4; r++) {
                int row = m0 + wm + mb * 16 + lq * 4 + r;
                int col = n0 + wn + nb * 16 + l16;
                if (OUT_BF16)
                    ((unsigned short*)Cp)[(size_t)row * ldc + col] = f2bf(acc[mb][nb][r]);
                else
                    ((float*)Cp)[(size_t)row * ldc + col] = acc[mb][nb][r];
            }
}

// ---------------- merged QK + Vt gemm (256 blocks = 1/CU) ------------------
__global__ __launch_bounds__(512, 1) void gemm_qkv_kernel(
        const unsigned short* __restrict__ x_bf,
        const unsigned short* __restrict__ Wqk,
        const unsigned short* __restrict__ Wv,
        unsigned short* __restrict__ QKb,
        unsigned short* __restrict__ Vtb) {
    __shared__ __align__(16) unsigned short sL[4 * 16384];   // 128 KB
    const int bid = blockIdx.x;
    if (bid < 192) {
        // QK = x @ [Wq;Wk]^T : M=4096 N=3072 (16 x 12 tiles of 256)
        gemm256_body<1>(x_bf, Wqk, QKb, 3072,
                        (bid / 12) * 256, (bid % 12) * 256, sL);
    } else {
        // Vt = Wv @ x^T : M=1024 N=4096 (4 x 16 tiles of 256)
        int t = bid - 192;
        gemm256_body<1>(Wv, x_bf, Vtb, 4096,
                        (t / 16) * 256, (t % 16) * 256, sL);
    }
}

// ---------------- O-proj gemm (fp32 out, 256 blocks = 1/CU) ----------------
__global__ __launch_bounds__(512, 1) void gemm_o_kernel(
        const unsigned short* __restrict__ A,
        const unsigned short* __restrict__ B,
        float* __restrict__ C) {
    __shared__ __align__(16) unsigned short sL[4 * 12288];   // 96 KB
    gemm128_body<0>(A, B, C, 2048,
                    blockIdx.y * 128, blockIdx.x * 256, sL);
}

// ---------------- flash attention v4 (proven plateau: ~99 us) ---------------
// Six structural variants (r0-r9) all land 99-112 us; this is the best.
// 4 waves = 4 q-slices (32 q-rows each), all 64 keys/wave; double-buffered
// sK/sV + wave-private sP (80 KB, 2 blocks/CU — grid 512 caps at 2/CU
// anyway, so LDS is free); two 32-key PV steps interleave with QK/softmax.
__global__ __launch_bounds__(256, 2) void flash_kernel(
        const unsigned short* __restrict__ QK,
        const unsigned short* __restrict__ Vt,
        unsigned short* __restrict__ O) {
    // layout (ushorts): sK[2][8192] @0, sV[2][8192] @16384, sP[4][2048] @32768
    __shared__ __align__(16) unsigned short smem[40960];

    const int tid  = threadIdx.x;
    const int wave = tid >> 6;
    const int lane = tid & 63;
    const int l16  = lane & 15;
    const int lq   = lane >> 4;
    const int qt   = blockIdx.x;          // 0..15 (128 tokens each)
    const int bh   = blockIdx.y;
    const int b    = bh >> 4;
    const int h    = bh & 15;
    const int kvh  = h >> 1;
    const size_t tokbase = (size_t)b * 2048 + qt * 128 + wave * 32;

    // Q fragments: 32 rows x 128 d per wave (B-operand, col = q = l16)
    short8 qf[2][4];
#pragma unroll
    for (int qb = 0; qb < 2; qb++) {
        const unsigned short* qp =
            QK + (tokbase + qb * 16 + l16) * 3072 + h * 128 + lq * 8;
#pragma unroll
        for (int c = 0; c < 4; c++) qf[qb][c] = *(const short8*)(qp + c * 32);
    }

    const unsigned short* gKe =
        QK + ((size_t)b * 2048 + wave * 16 + lq) * 3072 + 2048 + kvh * 128 +
        (l16 ^ lq) * 8;
    const unsigned short* gKo =
        QK + ((size_t)b * 2048 + wave * 16 + 4 + lq) * 3072 + 2048 + kvh * 128 +
        (l16 ^ (lq + 4)) * 8;
    const unsigned short* gV0 =
        Vt + (size_t)(kvh * 128 + wave * 32 + (lane >> 3)) * 4096 +
        (size_t)b * 2048 + ((lane & 7) ^ (lane >> 3)) * 8;

#define STAGE_KT(sKd, sVd)                                                     \
    do {                                                                       \
        _Pragma("unroll")                                                      \
        for (int i = 0; i < 4; i++) {                                          \
            const unsigned short* gk =                                         \
                ((i & 1) ? gKo : gKe) + (i >> 1) * 24576;                      \
            __builtin_amdgcn_global_load_lds(                                  \
                (const __attribute__((address_space(1))) void*)gk,             \
                (__attribute__((address_space(3))) void*)((sKd) +              \
                                                          (wave * 4 + i) * 512),\
                16, 0, 0);                                                     \
            __builtin_amdgcn_global_load_lds(                                  \
                (const __attribute__((address_space(1))) void*)(gV0 +          \
                                                               i * 32768),     \
                (__attribute__((address_space(3))) void*)((sVd) +              \
                                                          (wave * 4 + i) * 512),\
                16, 0, 0);                                                     \
        }                                                                      \
        gKe += 196608; gKo += 196608; gV0 += 64;                               \
    } while (0)

    unsigned short* pB = smem + 32768 + wave * 2048;

    floatx4 oacc[2][8] = {};
    float l_run[2] = {0.0f, 0.0f};

    STAGE_KT(smem, smem + 16384);
    asm volatile("s_waitcnt vmcnt(0)" ::: "memory");
    __builtin_amdgcn_s_barrier();
    asm volatile("" ::: "memory");

    for (int kt = 0; kt < 32; kt++) {
        const int cur = kt & 1;
        const unsigned short* sKc = smem + cur * 8192;
        const unsigned short* sVc = smem + 16384 + cur * 8192;
        if (kt < 31) {
            unsigned short* sKn = smem + (cur ^ 1) * 8192;
            unsigned short* sVn = smem + 16384 + (cur ^ 1) * 8192;
            STAGE_KT(sKn, sVn);
        }

        // ===== ks0: QK over kb=0,1 + softmax + P write (keys 0..31) =====
#pragma unroll
        for (int kb = 0; kb < 2; kb++) {
            floatx4 sacc[2] = {};
#pragma unroll
            for (int c = 0; c < 4; c++) {
                short8 kf = *(const short8*)(
                    sKc + (kb * 16 + l16) * 128 + (((c * 4 + lq) ^ (l16 & 7)) * 8));
#pragma unroll
                for (int qb = 0; qb < 2; qb++)
                    sacc[qb] = __builtin_amdgcn_mfma_f32_16x16x32_bf16(
                        kf, qf[qb][c], sacc[qb], 0, 0, 0);
            }
#pragma unroll
            for (int qb = 0; qb < 2; qb++) {
                float p0 = __builtin_exp2f(sacc[qb][0]);
                float p1 = __builtin_exp2f(sacc[qb][1]);
                float p2 = __builtin_exp2f(sacc[qb][2]);
                float p3 = __builtin_exp2f(sacc[qb][3]);
                l_run[qb] += (p0 + p1) + (p2 + p3);
                int row = qb * 16 + l16;
                uint2 u;
                u.x = pk_bf16(p0, p1);
                u.y = pk_bf16(p2, p3);
                *(uint2*)(pB + row * 64 +
                          (((kb * 2 + (lq >> 1)) ^ (row & 7)) * 8) +
                          (lq & 1) * 4) = u;
            }
        }
        asm volatile("s_waitcnt lgkmcnt(0)" ::: "memory");

        short8 pf0[2];
#pragma unroll
        for (int qb = 0; qb < 2; qb++) {
            int row = qb * 16 + l16;
            pf0[qb] = *(const short8*)(pB + row * 64 +
                                       ((lq ^ (row & 7)) * 8));
        }

        // ===== PV(ks0) =====
        __builtin_amdgcn_s_setprio(1);
#pragma unroll
        for (int nb = 0; nb < 8; nb++) {
            short8 vf = *(const short8*)(
                sVc + (nb * 16 + l16) * 64 + ((lq ^ (l16 & 7)) * 8));
#pragma unroll
            for (int qb = 0; qb < 2; qb++)
                oacc[qb][nb] = __builtin_amdgcn_mfma_f32_16x16x32_bf16(
                    vf, pf0[qb], oacc[qb][nb], 0, 0, 0);
        }
        __builtin_amdgcn_s_setprio(0);

        // ===== ks1: QK over kb=2,3 + softmax + P write (keys 32..63) =====
#pragma unroll
        for (int kb = 2; kb < 4; kb++) {
            floatx4 sacc[2] = {};
#pragma unroll
            for (int c = 0; c < 4; c++) {
                short8 kf = *(const short8*)(
                    sKc + (kb * 16 + l16) * 128 + (((c * 4 + lq) ^ (l16 & 7)) * 8));
#pragma unroll
                for (int qb = 0; qb < 2; qb++)
                    sacc[qb] = __builtin_amdgcn_mfma_f32_16x16x32_bf16(
                        kf, qf[qb][c], sacc[qb], 0, 0, 0);
            }
#pragma unroll
            for (int qb = 0; qb < 2; qb++) {
                float p0 = __builtin_exp2f(sacc[qb][0]);
                float p1 = __builtin_exp2f(sacc[qb][1]);
                float p2 = __builtin_exp2f(sacc[qb][2]);
                float p3 = __builtin_exp2f(sacc[qb][3]);
                l_run[qb] += (p0 + p1) + (p2 + p3);
                int row = qb * 16 + l16;
                uint2 u;
                u.x = pk_bf16(p0, p1);
                u.y = pk_bf16(p2, p3);
                *(uint2*)(pB + row * 64 +
                          (((kb * 2 + (lq >> 1)) ^ (row & 7)) * 8) +
                          (lq & 1) * 4) = u;
            }
        }
        asm volatile("s_waitcnt lgkmcnt(0)" ::: "memory");

        short8 pf1[2];
#pragma unroll
        for (int qb = 0; qb < 2; qb++) {
            int row = qb * 16 + l16;
            pf1[qb] = *(const short8*)(pB + row * 64 +
                                       (((4 + lq) ^ (row & 7)) * 8));
        }

        // ===== PV(ks1) =====
        __builtin_amdgcn_s_setprio(1);
#pragma unroll
        for (int nb = 0; nb < 8; nb++) {
            short8 vf = *(const short8*)(
                sVc + (nb * 16 + l16) * 64 + (((4 + lq) ^ (l16 & 7)) * 8));
#pragma unroll
            for (int qb = 0; qb < 2; qb++)
                oacc[qb][nb] = __builtin_amdgcn_mfma_f32_16x16x32_bf16(
                    vf, pf1[qb], oacc[qb][nb], 0, 0, 0);
        }
        __builtin_amdgcn_s_setprio(0);

        asm volatile("s_waitcnt vmcnt(0)" ::: "memory");
        __builtin_amdgcn_s_barrier();
        asm volatile("" ::: "memory");
    }
#undef STAGE_KT

#pragma unroll
    for (int qb = 0; qb < 2; qb++) {
        float l = l_run[qb];
        l += __shfl_xor(l, 16);
        l += __shfl_xor(l, 32);
        float inv = 1.0f / l;
        size_t row = (tokbase + qb * 16 + l16) * 2048 + h * 128;
#pragma unroll
        for (int nb = 0; nb < 8; nb++) {
            uint2 u;
            u.x = pk_bf16(oacc[qb][nb][0] * inv, oacc[qb][nb][1] * inv);
            u.y = pk_bf16(oacc[qb][nb][2] * inv, oacc[qb][nb][3] * inv);
            *(uint2*)(O + row + nb * 16 + lq * 4) = u;
        }
    }
}

// ---------------- launcher ----------------
extern "C" void kernel_launch(void* const* d_in, const int* in_sizes, int n_in,
                              void* d_out, int out_size, void* d_ws, size_t ws_size,
                              hipStream_t stream) {
    const float* x  = (const float*)d_in[0];
    const float* Wq = (const float*)d_in[1];
    const float* Wk = (const float*)d_in[2];
    const float* Wv = (const float*)d_in[3];
    const float* Wo = (const float*)d_in[4];

    char* ws = (char*)d_ws;
    unsigned short* x_bf   = (unsigned short*)(ws);               // 16 MB
    unsigned short* Wqk_bf = (unsigned short*)(ws + 16777216);    // 12 MB (Wq;Wk)
    unsigned short* Wv_bf  = (unsigned short*)(ws + 29360128);    // 4 MB
    unsigned short* Wo_bf  = (unsigned short*)(ws + 33554432);    // 8 MB
    unsigned short* QKb    = (unsigned short*)(ws + 41943040);    // 24 MB (4096x3072)
    unsigned short* Vtb    = (unsigned short*)(ws + 67108864);    // 8 MB  (1024x4096)
    unsigned short* Ob     = (unsigned short*)(ws + 75497472);    // 16 MB (4096x2048)

    cast_all_kernel<<<dim3(20480), 256, 0, stream>>>(
        x, Wq, Wk, Wv, Wo, x_bf, Wqk_bf, Wv_bf, Wo_bf);

    // QK = x @ [Wq;Wk]^T  and  Vt = Wv @ x^T (256 blocks = 1/CU, 512 thr)
    gemm_qkv_kernel<<<dim3(256), 512, 0, stream>>>(x_bf, Wqk_bf, Wv_bf, QKb, Vtb);

    // flash attention: 128 tokens/block
    flash_kernel<<<dim3(16, 32), 256, 0, stream>>>(QKb, Vtb, Ob);

    // out = O @ Wo^T : M=4096, N=2048, K=2048, fp32 out (32 x 8 tiles)
    gemm_o_kernel<<<dim3(8, 32), 512, 0, stream>>>(Ob, Wo_bf, (float*)d_out);
}